// Round 1
// 233.021 us; speedup vs baseline: 1.0710x; 1.0710x over previous
//
#include <hip/hip_runtime.h>
#include <math.h>

// GQA block. Round 7: occupancy + LDS-conflict pass.
// (a) attn: 64 q/block (16 q/wave) -> 1024 blocks = 4 blocks/CU (was 2);
//     K LDS layout t-major so ak frag reads are wave-contiguous 1KiB
//     ds_read_b128 (conflict-free); per-lane DMA *source* remapped, dest linear.
// (b) GEMM retiled 128x64 -> grids 768/512 blocks (3 / 2 per CU, was 1.5 / 1);
//     prep chunk order flipped to (hi16, k8, lo16) so A/B frag reads are
//     wave-contiguous 1KiB (conflict-free) while DMA staging stays linear.
// (c) attn epilogue emits ctx in the new chunk order.
// Shapes: B=2, T=2048, DIM=1024, H=16, HKV=4, HD=64.

#define B_   2
#define T_   2048
#define DIM_ 1024
#define NH   16
#define NKV  4
#define HD_  64
#define BT_  (B_ * T_)

typedef _Float16 half8_t __attribute__((ext_vector_type(8)));
typedef _Float16 half4_t __attribute__((ext_vector_type(4)));
typedef float    f32x4   __attribute__((ext_vector_type(4)));

__device__ __forceinline__ void async_copy16(_Float16* lds, const _Float16* g) {
    __builtin_amdgcn_global_load_lds(
        (const __attribute__((address_space(1))) void*)g,
        (__attribute__((address_space(3))) void*)lds, 16, 0, 0);
}

// ---------------------------------------------------------------------------
// Kernel 0: RoPE sincos table: tab[t*32+i] = (cos, sin)(t * 10000^(-i/32))
// ---------------------------------------------------------------------------
__global__ __launch_bounds__(256) void tab_kernel(float2* __restrict__ tab)
{
    int gid = blockIdx.x * 256 + threadIdx.x;   // 0..65535
    int t = gid >> 5, i = gid & 31;
    double invf = pow(10000.0, -(double)i / 32.0);
    double ang  = (double)t * invf;
    tab[gid] = make_float2((float)cos(ang), (float)sin(ang));
}

// ---------------------------------------------------------------------------
// Kernel 1: weight prep. fp32 W rows (2560: Wq|Wk|Wv|Wo) -> fp16 hi/lo planes.
// Chunk idx = (nb*32+kb)*512 + (nl>>4)*64 + k8*16 + (nl&15)
// holds W[nb*128+nl][kb*32+k8*8 .. +8].  Reads: 128 consecutive threads share
// one W row (coalesced); writes 16B-scattered (L2-absorbed).
// ---------------------------------------------------------------------------
__global__ __launch_bounds__(256) void prep_w_kernel(
    const float* __restrict__ Wq, const float* __restrict__ Wk,
    const float* __restrict__ Wv, const float* __restrict__ Wo,
    _Float16* __restrict__ Whi, _Float16* __restrict__ Wlo)
{
    int c = blockIdx.x * 256 + threadIdx.x;       // 0..327679
    int k8 = c & 3, kb = (c >> 2) & 31, nl = (c >> 7) & 127, nb = c >> 14;
    int n = nb * 128 + nl, k = kb * 32 + k8 * 8;
    const float* src;
    if (n < 1024)      src = Wq + (size_t)n * 1024;
    else if (n < 1280) src = Wk + (size_t)(n - 1024) * 1024;
    else if (n < 1536) src = Wv + (size_t)(n - 1280) * 1024;
    else               src = Wo + (size_t)(n - 1536) * 1024;
    float4 f0 = *(const float4*)(src + k);
    float4 f1 = *(const float4*)(src + k + 4);
    float xs[8] = {f0.x, f0.y, f0.z, f0.w, f1.x, f1.y, f1.z, f1.w};
    half8_t hi, lo;
#pragma unroll
    for (int j = 0; j < 8; ++j) {
        _Float16 h = (_Float16)xs[j];
        hi[j] = h;
        lo[j] = (_Float16)(xs[j] - (float)h);
    }
    size_t idx = (size_t)(nb * 32 + kb) * 512 + (nl >> 4) * 64 + k8 * 16 + (nl & 15);
    *(half8_t*)&Whi[idx * 8] = hi;
    *(half8_t*)&Wlo[idx * 8] = lo;
}

// ---------------------------------------------------------------------------
// Kernel 2: A prep: hs fp32 [4096 x 1024] -> fp16 chunks, same order as W.
// ---------------------------------------------------------------------------
__global__ __launch_bounds__(256) void prep_a_kernel(
    const float* __restrict__ hs, _Float16* __restrict__ Ah)
{
    int gid = blockIdx.x * 256 + threadIdx.x;    // 0..524287
    int k8 = gid & 3, kb = (gid >> 2) & 31, ml = (gid >> 7) & 127, mb = gid >> 14;
    const float* src = hs + (size_t)(mb * 128 + ml) * 1024 + kb * 32 + k8 * 8;
    float4 f0 = *(const float4*)src;
    float4 f1 = *(const float4*)(src + 4);
    half8_t hv;
    hv[0] = (_Float16)f0.x; hv[1] = (_Float16)f0.y;
    hv[2] = (_Float16)f0.z; hv[3] = (_Float16)f0.w;
    hv[4] = (_Float16)f1.x; hv[5] = (_Float16)f1.y;
    hv[6] = (_Float16)f1.z; hv[7] = (_Float16)f1.w;
    size_t idx = (size_t)(mb * 32 + kb) * 512 + (ml >> 4) * 64 + k8 * 16 + (ml & 15);
    *(half8_t*)&Ah[idx * 8] = hv;
}

// ---------------------------------------------------------------------------
// Kernel 3: 2-pass MFMA GEMM, all-DMA staging. C = A @ (Whi+Wlo)^T + bias.
// 128x64 tile, BK=32, dbuf. 4 waves as 2x2 (wm: 64 rows, wn: 32 cols).
// Frag reads are wave-contiguous 1KiB ds_read_b128 (bank-conflict-free).
// MODE 0: QKV epilogue (scatter fp32 [b,h,t,d]). MODE 1: row-major fp32 out.
// nj0/nj are 64-col tile indices into the 2560-row W plane.
// ---------------------------------------------------------------------------
template <int MODE>
__global__ __launch_bounds__(256, 3) void gemm2p_kernel(
    const _Float16* __restrict__ Ah,
    const _Float16* __restrict__ Whi, const _Float16* __restrict__ Wlo,
    int nj0,
    const float* __restrict__ bq, const float* __restrict__ bk,
    const float* __restrict__ bv,
    float* __restrict__ o0, float* __restrict__ o1, float* __restrict__ o2)
{
    __shared__ _Float16 sA [2][4096];
    __shared__ _Float16 sBh[2][2048];
    __shared__ _Float16 sBl[2][2048];

    const int tid  = threadIdx.x;
    const int w    = tid >> 6, lane = tid & 63;
    const int quad = lane >> 4, l15 = lane & 15;
    const int wm = w >> 1, wn = w & 1;
    const int mb   = blockIdx.y;
    const int nblk = blockIdx.x;
    const int nj   = nj0 + nblk;

    const _Float16* AB   = Ah  + (size_t)mb * 32 * 4096;
    const size_t woff = (size_t)(nj >> 1) * 32 * 4096 + (size_t)(nj & 1) * 2048;
    const _Float16* WhiB = Whi + woff;
    const _Float16* WloB = Wlo + woff;

    f32x4 acc[4][2];
#pragma unroll
    for (int mt = 0; mt < 4; ++mt)
#pragma unroll
        for (int nt = 0; nt < 2; ++nt) {
            f32x4 z = {0.f, 0.f, 0.f, 0.f};
            acc[mt][nt] = z;
        }

    // Per iter: A 512 chunks (2/thread), Bh 256 (1/thread), Bl 256 (1/thread).
#define GEMM_STAGE(buf, kbl)                                                  \
    {                                                                         \
        const _Float16* ga = AB   + (size_t)(kbl) * 4096;                     \
        const _Float16* gh = WhiB + (size_t)(kbl) * 4096;                     \
        const _Float16* gl = WloB + (size_t)(kbl) * 4096;                     \
        int cb = w * 64;                                                      \
        async_copy16(&sA [buf][cb * 8],         ga + (size_t)(cb + lane) * 8);        \
        async_copy16(&sA [buf][(cb + 256) * 8], ga + (size_t)(cb + 256 + lane) * 8);  \
        async_copy16(&sBh[buf][cb * 8],         gh + (size_t)(cb + lane) * 8);        \
        async_copy16(&sBl[buf][cb * 8],         gl + (size_t)(cb + lane) * 8);        \
    }

    GEMM_STAGE(0, 0);
    __syncthreads();

    for (int kb = 0; kb < 32; ++kb) {
        const int cur = kb & 1;
        if (kb + 1 < 32) { GEMM_STAGE(cur ^ 1, kb + 1); }

        half8_t af[4], bf[2], blv[2];
#pragma unroll
        for (int mt = 0; mt < 4; ++mt)
            af[mt] = *(const half8_t*)&sA[cur][(((wm * 4 + mt) * 64) + lane) * 8];
#pragma unroll
        for (int nt = 0; nt < 2; ++nt) {
            bf[nt]  = *(const half8_t*)&sBh[cur][(((wn * 2 + nt) * 64) + lane) * 8];
            blv[nt] = *(const half8_t*)&sBl[cur][(((wn * 2 + nt) * 64) + lane) * 8];
        }
#pragma unroll
        for (int mt = 0; mt < 4; ++mt)
#pragma unroll
            for (int nt = 0; nt < 2; ++nt) {
                acc[mt][nt] = __builtin_amdgcn_mfma_f32_16x16x32_f16(af[mt], bf[nt],  acc[mt][nt], 0, 0, 0);
                acc[mt][nt] = __builtin_amdgcn_mfma_f32_16x16x32_f16(af[mt], blv[nt], acc[mt][nt], 0, 0, 0);
            }
        __syncthreads();
    }

    const int m0 = mb * 128;
    if constexpr (MODE == 0) {
        int nreg = nj * 64;
        const float* bias; float* outp; int nh2, nbl;
        if (nreg < 1024)      { bias = bq; outp = o0; nh2 = NH;  nbl = nreg; }
        else if (nreg < 1280) { bias = bk; outp = o1; nh2 = NKV; nbl = nreg - 1024; }
        else                  { bias = bv; outp = o2; nh2 = NKV; nbl = nreg - 1280; }
        int hh = nbl >> 6;    // 64-col tiles are head-aligned (HD=64)
#pragma unroll
        for (int mt = 0; mt < 4; ++mt)
#pragma unroll
            for (int r = 0; r < 4; ++r) {
                int m  = m0 + wm * 64 + mt * 16 + quad * 4 + r;
                int b_ = m >> 11, t_ = m & 2047;
                float* cp = outp + (((size_t)(b_ * nh2 + hh)) * T_ + t_) * 64;
#pragma unroll
                for (int nt = 0; nt < 2; ++nt) {
                    int dd = wn * 32 + nt * 16 + l15;
                    cp[dd] = acc[mt][nt][r] + bias[hh * 64 + dd];
                }
            }
    } else {
        int n0 = nblk * 64 + wn * 32;
#pragma unroll
        for (int mt = 0; mt < 4; ++mt)
#pragma unroll
            for (int r = 0; r < 4; ++r) {
                int m = m0 + wm * 64 + mt * 16 + quad * 4 + r;
#pragma unroll
                for (int nt = 0; nt < 2; ++nt) {
                    int n = n0 + nt * 16 + l15;
                    o0[(size_t)m * 1024 + n] = acc[mt][nt][r] + bq[n];
                }
            }
    }
#undef GEMM_STAGE
}

// ---------------------------------------------------------------------------
// Kernel 4: RoPE via table, fp32 -> fp16 (q pre-scaled by 0.125).
// ---------------------------------------------------------------------------
__global__ __launch_bounds__(256) void rope_half_kernel(
    const float* __restrict__ qf, const float* __restrict__ kf,
    const float2* __restrict__ tab,
    _Float16* __restrict__ qh, _Float16* __restrict__ kh)
{
    int gid = blockIdx.x * 256 + threadIdx.x;
    int i   = gid & 31;
    int row = gid >> 5;
    const float* src; _Float16* dst; int t; float sc;
    if (row < B_ * NH * T_) {
        src = qf + (size_t)row * 64; dst = qh + (size_t)row * 64;
        t = row & (T_ - 1); sc = 0.125f;
    } else {
        int r = row - B_ * NH * T_;
        src = kf + (size_t)r * 64; dst = kh + (size_t)r * 64;
        t = r & (T_ - 1); sc = 1.0f;
    }
    float2 cs = tab[t * 32 + i];
    float c = cs.x, s = cs.y;
    float x0 = src[i], x1 = src[i + 32];
    float xe = src[2 * i], xo = src[2 * i + 1];
    dst[i]      = (_Float16)((x0 * c - xo * s) * sc);
    dst[i + 32] = (_Float16)((x1 * c + xe * s) * sc);
}

// ---------------------------------------------------------------------------
// Kernel 5: V transpose fp32 [b,hkv,t,d] -> fp16 [b,hkv,d,t].
// ---------------------------------------------------------------------------
__global__ __launch_bounds__(256) void vtrans_kernel(
    const float* __restrict__ vf, _Float16* __restrict__ vth)
{
    __shared__ float ts[64][65];
    const int bhk = blockIdx.y;
    const int t0  = blockIdx.x * 64;
    const int tid = threadIdx.x;
    const float* src = vf + (size_t)bhk * T_ * 64 + (size_t)t0 * 64;

    int row = tid >> 2, c0 = (tid & 3) * 16;
#pragma unroll
    for (int j = 0; j < 16; ++j)
        ts[row][c0 + j] = src[(size_t)row * 64 + c0 + j];
    __syncthreads();

    int drow = tid >> 2;
    _Float16* dst = vth + (size_t)bhk * 64 * T_ + (size_t)drow * T_ + t0 + c0;
    half8_t h0, h1;
#pragma unroll
    for (int j = 0; j < 8; ++j) h0[j] = (_Float16)ts[c0 + j][drow];
#pragma unroll
    for (int j = 0; j < 8; ++j) h1[j] = (_Float16)ts[c0 + 8 + j][drow];
    *(half8_t*)(dst)     = h0;
    *(half8_t*)(dst + 8) = h1;
}

// ---------------------------------------------------------------------------
// Kernel 6: flash attention. S^T = K Q^T -> exp() -> P register-direct as
// B-operand of 16x16x16 PV MFMAs (A=V^T-frags, out O^T[d][q]). Fixed-max
// softmax. 64 q/block (16 q/wave), 4 blocks/CU.
// K LDS chunk r*256 + t*64 + q*16 + l  <->  K[key=16t+l][d=8*(r*4+q)..+8]
//   (ak frag reads are wave-contiguous 1KiB -> conflict-free)
// V LDS chunk (g*4+dt)*16+l <-> V^T[d=16dt+l][key=8g..+8]  (unchanged)
// Epilogue: fp16 stores into the new chunk order for the out-GEMM.
// ---------------------------------------------------------------------------
__global__ __launch_bounds__(256, 4) void attn_kernel(
    const _Float16* __restrict__ qh, const _Float16* __restrict__ kh,
    const _Float16* __restrict__ vth, _Float16* __restrict__ ctx_h)
{
    __shared__ _Float16 Ks[2][4096];
    __shared__ _Float16 Vs[2][4096];

    const int qt = blockIdx.x;          // 0..31 (64-q tiles)
    const int bh = blockIdx.y;          // 0..31
    const int b  = bh >> 4, h = bh & 15, hk = h >> 2;
    const int tid  = threadIdx.x;
    const int w    = tid >> 6;
    const int lane = tid & 63;
    const int quad = lane >> 4, l15 = lane & 15;

    // Q B-frag: this wave owns q rows qt*64 + w*16 + l15 (q pre-scaled 0.125)
    const _Float16* Qb = qh +
        ((size_t)(b * NH + h) * T_ + qt * 64 + w * 16 + l15) * 64 + quad * 8;
    half8_t aq0 = *(const half8_t*)(Qb);
    half8_t aq1 = *(const half8_t*)(Qb + 32);

    const _Float16* Kb = kh  + (size_t)(b * NKV + hk) * (T_ * 64);
    const _Float16* Vb = vth + (size_t)(b * NKV + hk) * (64 * T_);

#define ATTN_STAGE(buf, ktile)                                                \
    {                                                                         \
        _Float16* kd = &Ks[buf][0];                                           \
        _Float16* vd = &Vs[buf][0];                                           \
        _Pragma("unroll")                                                     \
        for (int p = 0; p < 2; ++p) {                                         \
            int cb = p * 256 + w * 64;                                        \
            int c  = cb + lane;                                               \
            int kl = c & 15, kq = (c >> 4) & 3, ktt = (c >> 6) & 3, kr = c >> 8; \
            const _Float16* kg = Kb + ((size_t)((ktile) * 64 + ktt * 16 + kl)) * 64 + (kr * 4 + kq) * 8; \
            int l_ = c & 15, t_ = (c >> 4) & 3, g_ = c >> 6;                  \
            const _Float16* vg = Vb + ((size_t)(t_ * 16 + l_)) * T_ + (ktile) * 64 + g_ * 8; \
            async_copy16(kd + cb * 8, kg);                                    \
            async_copy16(vd + cb * 8, vg);                                    \
        }                                                                     \
    }

    float l_i = 0.0f;
    f32x4 o_acc[4];
#pragma unroll
    for (int dt = 0; dt < 4; ++dt) { f32x4 z = {0.f,0.f,0.f,0.f}; o_acc[dt] = z; }

    ATTN_STAGE(0, 0);
    __syncthreads();

    for (int kt = 0; kt < T_ / 64; ++kt) {
        const int cur = kt & 1;
        if (kt + 1 < T_ / 64) { ATTN_STAGE(cur ^ 1, kt + 1); }

        // K A-frags: wave-contiguous 1KiB reads; lane holds
        // K[key=16t+l15][d=8*quad..] (ak0) / d=8*(quad+4) (ak1)
        half8_t ak0[4], ak1[4];
#pragma unroll
        for (int t = 0; t < 4; ++t) {
            const _Float16* kr_ = &Ks[cur][(t * 64 + lane) * 8];
            ak0[t] = *(const half8_t*)(kr_);
            ak1[t] = *(const half8_t*)(kr_ + 2048);
        }
        // V A-frags (16x16x16): V^T[d=16dt+l15][key=16t+4*quad .. +4]
        half4_t av[4][4];
#pragma unroll
        for (int t = 0; t < 4; ++t)
#pragma unroll
            for (int dt = 0; dt < 4; ++dt) {
                int chunk = ((2 * t + (quad >> 1)) * 4 + dt) * 16 + l15;
                av[t][dt] = *(const half4_t*)&Vs[cur][chunk * 8 + 4 * (quad & 1)];
            }

        // S^T tiles: rows = keys (quad*4+r), cols = q (l15)
        f32x4 sv[4];
#pragma unroll
        for (int t = 0; t < 4; ++t) {
            f32x4 z = {0.f,0.f,0.f,0.f};
            z     = __builtin_amdgcn_mfma_f32_16x16x32_f16(ak0[t], aq0, z, 0, 0, 0);
            sv[t] = __builtin_amdgcn_mfma_f32_16x16x32_f16(ak1[t], aq1, z, 0, 0, 0);
        }
#pragma unroll
        for (int t = 0; t < 4; ++t) {
            float p0 = __expf(sv[t][0]);
            float p1 = __expf(sv[t][1]);
            float p2 = __expf(sv[t][2]);
            float p3 = __expf(sv[t][3]);
            l_i += (p0 + p1) + (p2 + p3);
            half4_t pb;
            pb[0] = (_Float16)p0; pb[1] = (_Float16)p1;
            pb[2] = (_Float16)p2; pb[3] = (_Float16)p3;
#pragma unroll
            for (int dt = 0; dt < 4; ++dt)
                o_acc[dt] = __builtin_amdgcn_mfma_f32_16x16x16f16(
                    av[t][dt], pb, o_acc[dt], 0, 0, 0);
        }
        __syncthreads();
    }

    // epilogue: reduce l across quads (lane bits 4,5), normalize, store fp16
    // into new-order ctx chunks. O^T value at (quad,l15): d=16dt+4quad+r, q=l15.
    float l = l_i;
    l += __shfl_xor(l, 16);
    l += __shfl_xor(l, 32);
    float inv = 1.0f / l;
    const int mb   = b * 16 + (qt >> 1);
    const int mlhi = (qt & 1) * 4 + w;
#pragma unroll
    for (int dt = 0; dt < 4; ++dt)
#pragma unroll
        for (int r = 0; r < 4; ++r) {
            int d  = 16 * dt + 4 * quad + r;
            int kb = 2 * h + (d >> 5);
            int k8 = (d >> 3) & 3;
            int j  = d & 7;
            size_t idx = (size_t)(mb * 32 + kb) * 512 + mlhi * 64 + k8 * 16 + l15;
            ctx_h[idx * 8 + j] = (_Float16)(o_acc[dt][r] * inv);
        }
#undef ATTN_STAGE
}

// ---------------------------------------------------------------------------
extern "C" void kernel_launch(void* const* d_in, const int* in_sizes, int n_in,
                              void* d_out, int out_size, void* d_ws, size_t ws_size,
                              hipStream_t stream)
{
    const float* hs = (const float*)d_in[0];
    const float* Wq = (const float*)d_in[1];
    const float* bq = (const float*)d_in[2];
    const float* Wk = (const float*)d_in[3];
    const float* bk = (const float*)d_in[4];
    const float* Wv = (const float*)d_in[5];
    const float* bv = (const float*)d_in[6];
    const float* Wo = (const float*)d_in[7];
    const float* bo = (const float*)d_in[8];
    float* out = (float*)d_out;

    const size_t MB = 1024 * 1024;
    if (ws_size < 46 * MB) return;

    char* w = (char*)d_ws;
    _Float16* Whi  = (_Float16*)(w);             // 5 MB  [0,5)
    _Float16* Wlo  = (_Float16*)(w + 5 * MB);    // 5 MB  [5,10)
    float*    qf32 = (float*)(w + 10 * MB);      // 16 MB [10,26)
    float*    kf32 = (float*)(w + 26 * MB);      // 4 MB  [26,30)
    float*    vf32 = (float*)(w + 30 * MB);      // 4 MB  [30,34)
    _Float16* qh   = (_Float16*)(w + 34 * MB);   // 8 MB  [34,42)
    _Float16* kh   = (_Float16*)(w + 42 * MB);   // 2 MB  [42,44)
    _Float16* vth  = (_Float16*)(w + 44 * MB);   // 2 MB  [44,46)
    // aliases (lifetimes disjoint):
    _Float16* hs_h  = qh;                        // dead once rope writes qh
    float2*   tab   = (float2*)vth;              // dead once vtrans writes vth
    _Float16* ctx_h = (_Float16*)qf32;           // qf32 dead after rope

    tab_kernel<<<256, 256, 0, stream>>>(tab);
    prep_w_kernel<<<1280, 256, 0, stream>>>(Wq, Wk, Wv, Wo, Whi, Wlo);
    prep_a_kernel<<<2048, 256, 0, stream>>>(hs, hs_h);
    gemm2p_kernel<0><<<dim3(24, 32), 256, 0, stream>>>(
        hs_h, Whi, Wlo, 0, bq, bk, bv, qf32, kf32, vf32);
    rope_half_kernel<<<(B_ * (NH + NKV) * T_ * 32) / 256, 256, 0, stream>>>(
        qf32, kf32, tab, qh, kh);
    vtrans_kernel<<<dim3(T_ / 64, B_ * NKV), 256, 0, stream>>>(vf32, vth);
    attn_kernel<<<dim3(T_ / 64, B_ * NH), 256, 0, stream>>>(qh, kh, vth, ctx_h);
    gemm2p_kernel<1><<<dim3(16, 32), 256, 0, stream>>>(
        ctx_h, Whi, Wlo, 24, bo, nullptr, nullptr, out, nullptr, nullptr);
}

// Round 2
// 221.523 us; speedup vs baseline: 1.1266x; 1.0519x over previous
//
#include <hip/hip_runtime.h>
#include <math.h>

// GQA block. Round 8: attn back to 32 q/wave (r6 geometry: best LDS-traffic
// ratio) + counted-vmcnt software pipeline (raw s_barrier, no vmcnt(0) drain)
// + setprio around MFMA clusters. K LDS layout t-major (wave-contiguous 1KiB
// frag reads). GEMM/prep kernels unchanged from round 7 (they won there).
// Shapes: B=2, T=2048, DIM=1024, H=16, HKV=4, HD=64.

#define B_   2
#define T_   2048
#define DIM_ 1024
#define NH   16
#define NKV  4
#define HD_  64
#define BT_  (B_ * T_)

typedef _Float16 half8_t __attribute__((ext_vector_type(8)));
typedef _Float16 half4_t __attribute__((ext_vector_type(4)));
typedef float    f32x4   __attribute__((ext_vector_type(4)));

__device__ __forceinline__ void async_copy16(_Float16* lds, const _Float16* g) {
    __builtin_amdgcn_global_load_lds(
        (const __attribute__((address_space(1))) void*)g,
        (__attribute__((address_space(3))) void*)lds, 16, 0, 0);
}

#define VMCNT(n) asm volatile("s_waitcnt vmcnt(" #n ")" ::: "memory")
#define LGKMCNT0() asm volatile("s_waitcnt lgkmcnt(0)" ::: "memory")

__device__ __forceinline__ void wg_barrier() {
    asm volatile("" ::: "memory");
    __builtin_amdgcn_s_barrier();
    asm volatile("" ::: "memory");
}

// ---------------------------------------------------------------------------
// Kernel 0: RoPE sincos table: tab[t*32+i] = (cos, sin)(t * 10000^(-i/32))
// ---------------------------------------------------------------------------
__global__ __launch_bounds__(256) void tab_kernel(float2* __restrict__ tab)
{
    int gid = blockIdx.x * 256 + threadIdx.x;   // 0..65535
    int t = gid >> 5, i = gid & 31;
    double invf = pow(10000.0, -(double)i / 32.0);
    double ang  = (double)t * invf;
    tab[gid] = make_float2((float)cos(ang), (float)sin(ang));
}

// ---------------------------------------------------------------------------
// Kernel 1: weight prep. fp32 W rows (2560: Wq|Wk|Wv|Wo) -> fp16 hi/lo planes.
// Chunk idx = (nb*32+kb)*512 + (nl>>4)*64 + k8*16 + (nl&15)
// holds W[nb*128+nl][kb*32+k8*8 .. +8].
// ---------------------------------------------------------------------------
__global__ __launch_bounds__(256) void prep_w_kernel(
    const float* __restrict__ Wq, const float* __restrict__ Wk,
    const float* __restrict__ Wv, const float* __restrict__ Wo,
    _Float16* __restrict__ Whi, _Float16* __restrict__ Wlo)
{
    int c = blockIdx.x * 256 + threadIdx.x;       // 0..327679
    int k8 = c & 3, kb = (c >> 2) & 31, nl = (c >> 7) & 127, nb = c >> 14;
    int n = nb * 128 + nl, k = kb * 32 + k8 * 8;
    const float* src;
    if (n < 1024)      src = Wq + (size_t)n * 1024;
    else if (n < 1280) src = Wk + (size_t)(n - 1024) * 1024;
    else if (n < 1536) src = Wv + (size_t)(n - 1280) * 1024;
    else               src = Wo + (size_t)(n - 1536) * 1024;
    float4 f0 = *(const float4*)(src + k);
    float4 f1 = *(const float4*)(src + k + 4);
    float xs[8] = {f0.x, f0.y, f0.z, f0.w, f1.x, f1.y, f1.z, f1.w};
    half8_t hi, lo;
#pragma unroll
    for (int j = 0; j < 8; ++j) {
        _Float16 h = (_Float16)xs[j];
        hi[j] = h;
        lo[j] = (_Float16)(xs[j] - (float)h);
    }
    size_t idx = (size_t)(nb * 32 + kb) * 512 + (nl >> 4) * 64 + k8 * 16 + (nl & 15);
    *(half8_t*)&Whi[idx * 8] = hi;
    *(half8_t*)&Wlo[idx * 8] = lo;
}

// ---------------------------------------------------------------------------
// Kernel 2: A prep: hs fp32 [4096 x 1024] -> fp16 chunks, same order as W.
// ---------------------------------------------------------------------------
__global__ __launch_bounds__(256) void prep_a_kernel(
    const float* __restrict__ hs, _Float16* __restrict__ Ah)
{
    int gid = blockIdx.x * 256 + threadIdx.x;    // 0..524287
    int k8 = gid & 3, kb = (gid >> 2) & 31, ml = (gid >> 7) & 127, mb = gid >> 14;
    const float* src = hs + (size_t)(mb * 128 + ml) * 1024 + kb * 32 + k8 * 8;
    float4 f0 = *(const float4*)src;
    float4 f1 = *(const float4*)(src + 4);
    half8_t hv;
    hv[0] = (_Float16)f0.x; hv[1] = (_Float16)f0.y;
    hv[2] = (_Float16)f0.z; hv[3] = (_Float16)f0.w;
    hv[4] = (_Float16)f1.x; hv[5] = (_Float16)f1.y;
    hv[6] = (_Float16)f1.z; hv[7] = (_Float16)f1.w;
    size_t idx = (size_t)(mb * 32 + kb) * 512 + (ml >> 4) * 64 + k8 * 16 + (ml & 15);
    *(half8_t*)&Ah[idx * 8] = hv;
}

// ---------------------------------------------------------------------------
// Kernel 3: 2-pass MFMA GEMM, all-DMA staging. C = A @ (Whi+Wlo)^T + bias.
// 128x64 tile, BK=32, dbuf, 4 waves as 2x2. Unchanged from round 7.
// ---------------------------------------------------------------------------
template <int MODE>
__global__ __launch_bounds__(256, 3) void gemm2p_kernel(
    const _Float16* __restrict__ Ah,
    const _Float16* __restrict__ Whi, const _Float16* __restrict__ Wlo,
    int nj0,
    const float* __restrict__ bq, const float* __restrict__ bk,
    const float* __restrict__ bv,
    float* __restrict__ o0, float* __restrict__ o1, float* __restrict__ o2)
{
    __shared__ _Float16 sA [2][4096];
    __shared__ _Float16 sBh[2][2048];
    __shared__ _Float16 sBl[2][2048];

    const int tid  = threadIdx.x;
    const int w    = tid >> 6, lane = tid & 63;
    const int quad = lane >> 4, l15 = lane & 15;
    const int wm = w >> 1, wn = w & 1;
    const int mb   = blockIdx.y;
    const int nblk = blockIdx.x;
    const int nj   = nj0 + nblk;

    const _Float16* AB   = Ah  + (size_t)mb * 32 * 4096;
    const size_t woff = (size_t)(nj >> 1) * 32 * 4096 + (size_t)(nj & 1) * 2048;
    const _Float16* WhiB = Whi + woff;
    const _Float16* WloB = Wlo + woff;

    f32x4 acc[4][2];
#pragma unroll
    for (int mt = 0; mt < 4; ++mt)
#pragma unroll
        for (int nt = 0; nt < 2; ++nt) {
            f32x4 z = {0.f, 0.f, 0.f, 0.f};
            acc[mt][nt] = z;
        }

#define GEMM_STAGE(buf, kbl)                                                  \
    {                                                                         \
        const _Float16* ga = AB   + (size_t)(kbl) * 4096;                     \
        const _Float16* gh = WhiB + (size_t)(kbl) * 4096;                     \
        const _Float16* gl = WloB + (size_t)(kbl) * 4096;                     \
        int cb = w * 64;                                                      \
        async_copy16(&sA [buf][cb * 8],         ga + (size_t)(cb + lane) * 8);        \
        async_copy16(&sA [buf][(cb + 256) * 8], ga + (size_t)(cb + 256 + lane) * 8);  \
        async_copy16(&sBh[buf][cb * 8],         gh + (size_t)(cb + lane) * 8);        \
        async_copy16(&sBl[buf][cb * 8],         gl + (size_t)(cb + lane) * 8);        \
    }

    GEMM_STAGE(0, 0);
    __syncthreads();

    for (int kb = 0; kb < 32; ++kb) {
        const int cur = kb & 1;
        if (kb + 1 < 32) { GEMM_STAGE(cur ^ 1, kb + 1); }

        half8_t af[4], bf[2], blv[2];
#pragma unroll
        for (int mt = 0; mt < 4; ++mt)
            af[mt] = *(const half8_t*)&sA[cur][(((wm * 4 + mt) * 64) + lane) * 8];
#pragma unroll
        for (int nt = 0; nt < 2; ++nt) {
            bf[nt]  = *(const half8_t*)&sBh[cur][(((wn * 2 + nt) * 64) + lane) * 8];
            blv[nt] = *(const half8_t*)&sBl[cur][(((wn * 2 + nt) * 64) + lane) * 8];
        }
#pragma unroll
        for (int mt = 0; mt < 4; ++mt)
#pragma unroll
            for (int nt = 0; nt < 2; ++nt) {
                acc[mt][nt] = __builtin_amdgcn_mfma_f32_16x16x32_f16(af[mt], bf[nt],  acc[mt][nt], 0, 0, 0);
                acc[mt][nt] = __builtin_amdgcn_mfma_f32_16x16x32_f16(af[mt], blv[nt], acc[mt][nt], 0, 0, 0);
            }
        __syncthreads();
    }

    const int m0 = mb * 128;
    if constexpr (MODE == 0) {
        int nreg = nj * 64;
        const float* bias; float* outp; int nh2, nbl;
        if (nreg < 1024)      { bias = bq; outp = o0; nh2 = NH;  nbl = nreg; }
        else if (nreg < 1280) { bias = bk; outp = o1; nh2 = NKV; nbl = nreg - 1024; }
        else                  { bias = bv; outp = o2; nh2 = NKV; nbl = nreg - 1280; }
        int hh = nbl >> 6;
#pragma unroll
        for (int mt = 0; mt < 4; ++mt)
#pragma unroll
            for (int r = 0; r < 4; ++r) {
                int m  = m0 + wm * 64 + mt * 16 + quad * 4 + r;
                int b_ = m >> 11, t_ = m & 2047;
                float* cp = outp + (((size_t)(b_ * nh2 + hh)) * T_ + t_) * 64;
#pragma unroll
                for (int nt = 0; nt < 2; ++nt) {
                    int dd = wn * 32 + nt * 16 + l15;
                    cp[dd] = acc[mt][nt][r] + bias[hh * 64 + dd];
                }
            }
    } else {
        int n0 = nblk * 64 + wn * 32;
#pragma unroll
        for (int mt = 0; mt < 4; ++mt)
#pragma unroll
            for (int r = 0; r < 4; ++r) {
                int m = m0 + wm * 64 + mt * 16 + quad * 4 + r;
#pragma unroll
                for (int nt = 0; nt < 2; ++nt) {
                    int n = n0 + nt * 16 + l15;
                    o0[(size_t)m * 1024 + n] = acc[mt][nt][r] + bq[n];
                }
            }
    }
#undef GEMM_STAGE
}

// ---------------------------------------------------------------------------
// Kernel 4: RoPE via table, fp32 -> fp16 (q pre-scaled by 0.125).
// ---------------------------------------------------------------------------
__global__ __launch_bounds__(256) void rope_half_kernel(
    const float* __restrict__ qf, const float* __restrict__ kf,
    const float2* __restrict__ tab,
    _Float16* __restrict__ qh, _Float16* __restrict__ kh)
{
    int gid = blockIdx.x * 256 + threadIdx.x;
    int i   = gid & 31;
    int row = gid >> 5;
    const float* src; _Float16* dst; int t; float sc;
    if (row < B_ * NH * T_) {
        src = qf + (size_t)row * 64; dst = qh + (size_t)row * 64;
        t = row & (T_ - 1); sc = 0.125f;
    } else {
        int r = row - B_ * NH * T_;
        src = kf + (size_t)r * 64; dst = kh + (size_t)r * 64;
        t = r & (T_ - 1); sc = 1.0f;
    }
    float2 cs = tab[t * 32 + i];
    float c = cs.x, s = cs.y;
    float x0 = src[i], x1 = src[i + 32];
    float xe = src[2 * i], xo = src[2 * i + 1];
    dst[i]      = (_Float16)((x0 * c - xo * s) * sc);
    dst[i + 32] = (_Float16)((x1 * c + xe * s) * sc);
}

// ---------------------------------------------------------------------------
// Kernel 5: V transpose fp32 [b,hkv,t,d] -> fp16 [b,hkv,d,t].
// ---------------------------------------------------------------------------
__global__ __launch_bounds__(256) void vtrans_kernel(
    const float* __restrict__ vf, _Float16* __restrict__ vth)
{
    __shared__ float ts[64][65];
    const int bhk = blockIdx.y;
    const int t0  = blockIdx.x * 64;
    const int tid = threadIdx.x;
    const float* src = vf + (size_t)bhk * T_ * 64 + (size_t)t0 * 64;

    int row = tid >> 2, c0 = (tid & 3) * 16;
#pragma unroll
    for (int j = 0; j < 16; ++j)
        ts[row][c0 + j] = src[(size_t)row * 64 + c0 + j];
    __syncthreads();

    int drow = tid >> 2;
    _Float16* dst = vth + (size_t)bhk * 64 * T_ + (size_t)drow * T_ + t0 + c0;
    half8_t h0, h1;
#pragma unroll
    for (int j = 0; j < 8; ++j) h0[j] = (_Float16)ts[c0 + j][drow];
#pragma unroll
    for (int j = 0; j < 8; ++j) h1[j] = (_Float16)ts[c0 + 8 + j][drow];
    *(half8_t*)(dst)     = h0;
    *(half8_t*)(dst + 8) = h1;
}

// ---------------------------------------------------------------------------
// Kernel 6: flash attention, 128 q/block, 32 q/wave (2 strips of 16).
// S^T = K Q^T -> exp() -> P register-direct into 16x16x16 PV MFMAs.
// Counted-vmcnt pipeline: stage(t+1) stays in flight across the compute of
// tile t (vmcnt(4), never 0 in steady state); raw s_barrier (no drain);
// lgkmcnt(0)+barrier protects buffer overwrite. setprio(1) around MFMAs.
// K LDS chunk kr*256 + t*64 + kq*16 + l <-> K[key=16t+l][d=8*(kr*4+kq)..+8]
//   (ak frag reads wave-contiguous 1KiB, conflict-free)
// V LDS chunk (g*4+dt)*16+l <-> V^T[d=16dt+l][key=8g..+8]
// Epilogue: fp16 stores into the (ml>>4, k8, ml&15) ctx chunk order.
// ---------------------------------------------------------------------------
__global__ __launch_bounds__(256, 2) void attn_kernel(
    const _Float16* __restrict__ qh, const _Float16* __restrict__ kh,
    const _Float16* __restrict__ vth, _Float16* __restrict__ ctx_h)
{
    __shared__ _Float16 Ks[2][4096];
    __shared__ _Float16 Vs[2][4096];

    const int qt = blockIdx.x;          // 0..15 (128-q tiles)
    const int bh = blockIdx.y;          // 0..31
    const int b  = bh >> 4, h = bh & 15, hk = h >> 2;
    const int tid  = threadIdx.x;
    const int w    = tid >> 6;
    const int lane = tid & 63;
    const int quad = lane >> 4, l15 = lane & 15;

    // Q B-frags for 2 strips of 16 q-rows (q pre-scaled by 0.125 at rope)
    half8_t aq0[2], aq1[2];
#pragma unroll
    for (int s = 0; s < 2; ++s) {
        const _Float16* Qb = qh +
            ((size_t)(b * NH + h) * T_ + qt * 128 + w * 32 + s * 16 + l15) * 64 + quad * 8;
        aq0[s] = *(const half8_t*)(Qb);
        aq1[s] = *(const half8_t*)(Qb + 32);
    }
    // Force Q loads resolved here -> no compiler vmcnt waits inside the loop.
    asm volatile("" :: "v"(aq0[0]), "v"(aq0[1]), "v"(aq1[0]), "v"(aq1[1]));

    const _Float16* Kb = kh  + (size_t)(b * NKV + hk) * (T_ * 64);
    const _Float16* Vb = vth + (size_t)(b * NKV + hk) * (64 * T_);

#define ATTN_STAGE(buf, ktile)                                                \
    {                                                                         \
        _Float16* kd = &Ks[buf][0];                                           \
        _Float16* vd = &Vs[buf][0];                                           \
        _Pragma("unroll")                                                     \
        for (int p = 0; p < 2; ++p) {                                         \
            int cb = p * 256 + w * 64;                                        \
            int c  = cb + lane;                                               \
            int kl = c & 15, kq = (c >> 4) & 3, ktt = (c >> 6) & 3, kr = c >> 8; \
            const _Float16* kg = Kb + ((size_t)((ktile) * 64 + ktt * 16 + kl)) * 64 + (kr * 4 + kq) * 8; \
            int l_ = c & 15, t_ = (c >> 4) & 3, g_ = c >> 6;                  \
            const _Float16* vg = Vb + ((size_t)(t_ * 16 + l_)) * T_ + (ktile) * 64 + g_ * 8; \
            async_copy16(kd + cb * 8, kg);                                    \
            async_copy16(vd + cb * 8, vg);                                    \
        }                                                                     \
    }

    float l_i[2] = {0.0f, 0.0f};
    f32x4 o_acc[2][4];
#pragma unroll
    for (int s = 0; s < 2; ++s)
#pragma unroll
        for (int dt = 0; dt < 4; ++dt) { f32x4 z = {0.f,0.f,0.f,0.f}; o_acc[s][dt] = z; }

    ATTN_STAGE(0, 0);

    for (int kt = 0; kt < T_ / 64; ++kt) {
        const int cur = kt & 1;
        if (kt + 1 < T_ / 64) {
            ATTN_STAGE(cur ^ 1, kt + 1);
            VMCNT(4);           // wait stage(cur) only; stage(cur^1) in flight
        } else {
            VMCNT(0);
        }
        wg_barrier();           // buf[cur] ready across all waves

        // K A-frags: wave-contiguous 1KiB reads
        half8_t ak0[4], ak1[4];
#pragma unroll
        for (int t = 0; t < 4; ++t) {
            const _Float16* kr_ = &Ks[cur][(t * 64 + lane) * 8];
            ak0[t] = *(const half8_t*)(kr_);
            ak1[t] = *(const half8_t*)(kr_ + 2048);
        }
        // V A-frags (16x16x16): V^T[d=16dt+l15][key=16t+4*quad .. +4]
        half4_t av[4][4];
#pragma unroll
        for (int t = 0; t < 4; ++t)
#pragma unroll
            for (int dt = 0; dt < 4; ++dt) {
                int chunk = ((2 * t + (quad >> 1)) * 4 + dt) * 16 + l15;
                av[t][dt] = *(const half4_t*)&Vs[cur][chunk * 8 + 4 * (quad & 1)];
            }

#pragma unroll
        for (int s = 0; s < 2; ++s) {
            // S^T tiles: rows = keys (quad*4+r), cols = q (l15)
            f32x4 sv[4];
            __builtin_amdgcn_s_setprio(1);
#pragma unroll
            for (int t = 0; t < 4; ++t) {
                f32x4 z = {0.f,0.f,0.f,0.f};
                z     = __builtin_amdgcn_mfma_f32_16x16x32_f16(ak0[t], aq0[s], z, 0, 0, 0);
                sv[t] = __builtin_amdgcn_mfma_f32_16x16x32_f16(ak1[t], aq1[s], z, 0, 0, 0);
            }
            __builtin_amdgcn_s_setprio(0);
#pragma unroll
            for (int t = 0; t < 4; ++t) {
                float p0 = __expf(sv[t][0]);
                float p1 = __expf(sv[t][1]);
                float p2 = __expf(sv[t][2]);
                float p3 = __expf(sv[t][3]);
                l_i[s] += (p0 + p1) + (p2 + p3);
                half4_t pb;
                pb[0] = (_Float16)p0; pb[1] = (_Float16)p1;
                pb[2] = (_Float16)p2; pb[3] = (_Float16)p3;
                __builtin_amdgcn_s_setprio(1);
#pragma unroll
                for (int dt = 0; dt < 4; ++dt)
                    o_acc[s][dt] = __builtin_amdgcn_mfma_f32_16x16x16f16(
                        av[t][dt], pb, o_acc[s][dt], 0, 0, 0);
                __builtin_amdgcn_s_setprio(0);
            }
        }
        LGKMCNT0();             // all LDS reads of buf[cur] retired
        wg_barrier();           // safe for next iter's DMA to overwrite
    }

    // epilogue: reduce l across quads (lane bits 4,5), normalize, store fp16
    // into ctx chunks: idx = (mb*32+kb)*512 + (ml>>4)*64 + k8*16 + (ml&15)
    const int mb = b * 16 + qt;
#pragma unroll
    for (int s = 0; s < 2; ++s) {
        float l = l_i[s];
        l += __shfl_xor(l, 16);
        l += __shfl_xor(l, 32);
        float inv = 1.0f / l;
        // ml = w*32 + s*16 + l15  ->  ml>>4 = 2w+s, ml&15 = l15
#pragma unroll
        for (int dt = 0; dt < 4; ++dt)
#pragma unroll
            for (int r = 0; r < 4; ++r) {
                int d   = 16 * dt + 4 * quad + r;
                int kb_ = 2 * h + (d >> 5);
                int k8  = (d >> 3) & 3;
                int j   = d & 7;
                size_t idx = (size_t)(mb * 32 + kb_) * 512 + (w * 2 + s) * 64 + k8 * 16 + l15;
                ctx_h[idx * 8 + j] = (_Float16)(o_acc[s][dt][r] * inv);
            }
    }
#undef ATTN_STAGE
}

// ---------------------------------------------------------------------------
extern "C" void kernel_launch(void* const* d_in, const int* in_sizes, int n_in,
                              void* d_out, int out_size, void* d_ws, size_t ws_size,
                              hipStream_t stream)
{
    const float* hs = (const float*)d_in[0];
    const float* Wq = (const float*)d_in[1];
    const float* bq = (const float*)d_in[2];
    const float* Wk = (const float*)d_in[3];
    const float* bk = (const float*)d_in[4];
    const float* Wv = (const float*)d_in[5];
    const float* bv = (const float*)d_in[6];
    const float* Wo = (const float*)d_in[7];
    const float* bo = (const float*)d_in[8];
    float* out = (float*)d_out;

    const size_t MB = 1024 * 1024;
    if (ws_size < 46 * MB) return;

    char* w = (char*)d_ws;
    _Float16* Whi  = (_Float16*)(w);             // 5 MB  [0,5)
    _Float16* Wlo  = (_Float16*)(w + 5 * MB);    // 5 MB  [5,10)
    float*    qf32 = (float*)(w + 10 * MB);      // 16 MB [10,26)
    float*    kf32 = (float*)(w + 26 * MB);      // 4 MB  [26,30)
    float*    vf32 = (float*)(w + 30 * MB);      // 4 MB  [30,34)
    _Float16* qh   = (_Float16*)(w + 34 * MB);   // 8 MB  [34,42)
    _Float16* kh   = (_Float16*)(w + 42 * MB);   // 2 MB  [42,44)
    _Float16* vth  = (_Float16*)(w + 44 * MB);   // 2 MB  [44,46)
    // aliases (lifetimes disjoint):
    _Float16* hs_h  = qh;                        // dead once rope writes qh
    float2*   tab   = (float2*)vth;              // dead once vtrans writes vth
    _Float16* ctx_h = (_Float16*)qf32;           // qf32 dead after rope

    tab_kernel<<<256, 256, 0, stream>>>(tab);
    prep_w_kernel<<<1280, 256, 0, stream>>>(Wq, Wk, Wv, Wo, Whi, Wlo);
    prep_a_kernel<<<2048, 256, 0, stream>>>(hs, hs_h);
    gemm2p_kernel<0><<<dim3(24, 32), 256, 0, stream>>>(
        hs_h, Whi, Wlo, 0, bq, bk, bv, qf32, kf32, vf32);
    rope_half_kernel<<<(B_ * (NH + NKV) * T_ * 32) / 256, 256, 0, stream>>>(
        qf32, kf32, tab, qh, kh);
    vtrans_kernel<<<dim3(T_ / 64, B_ * NKV), 256, 0, stream>>>(vf32, vth);
    attn_kernel<<<dim3(T_ / 128, B_ * NH), 256, 0, stream>>>(qh, kh, vth, ctx_h);
    gemm2p_kernel<1><<<dim3(16, 32), 256, 0, stream>>>(
        ctx_h, Whi, Wlo, 24, bo, nullptr, nullptr, out, nullptr, nullptr);
}

// Round 5
// 206.498 us; speedup vs baseline: 1.2086x; 1.0728x over previous
//
#include <hip/hip_runtime.h>
#include <math.h>

// GQA block. Round 9 (3rd submit; two infra failures, kernel never measured).
// (a) KVBLK=128: two 64-key tiles per barrier pair (16 iters, was 32) ->
//     halves barrier/drain overhead. LDS 64KB/block, 2 blocks/CU.
// (b) V pre-interleaved in global (vtrans) so attn V frag reads are
//     wave-contiguous 1KiB ds_read_b128 (conflict-free; was 4-way b64).
//     DMA source for V is fully linear.
// (c) all setprio removed (20 sched fences/iter caused the r8 regression).
// (d) counted vmcnt(8) pipeline + raw s_barrier retained (pattern validated
//     in r8 at KVBLK=64: passed, absmax 2.4e-4).
// GEMM/prep kernels unchanged. Shapes: B=2, T=2048, DIM=1024, H=16, HKV=4, HD=64.

#define B_   2
#define T_   2048
#define DIM_ 1024
#define NH   16
#define NKV  4
#define HD_  64
#define BT_  (B_ * T_)

typedef _Float16 half8_t __attribute__((ext_vector_type(8)));
typedef _Float16 half4_t __attribute__((ext_vector_type(4)));
typedef float    f32x4   __attribute__((ext_vector_type(4)));

__device__ __forceinline__ void async_copy16(_Float16* lds, const _Float16* g) {
    __builtin_amdgcn_global_load_lds(
        (const __attribute__((address_space(1))) void*)g,
        (__attribute__((address_space(3))) void*)lds, 16, 0, 0);
}

#define VMCNT(n) asm volatile("s_waitcnt vmcnt(" #n ")" ::: "memory")
#define LGKMCNT0() asm volatile("s_waitcnt lgkmcnt(0)" ::: "memory")

__device__ __forceinline__ void wg_barrier() {
    asm volatile("" ::: "memory");
    __builtin_amdgcn_s_barrier();
    asm volatile("" ::: "memory");
}

// ---------------------------------------------------------------------------
// Kernel 0: RoPE sincos table: tab[t*32+i] = (cos, sin)(t * 10000^(-i/32))
// ---------------------------------------------------------------------------
__global__ __launch_bounds__(256) void tab_kernel(float2* __restrict__ tab)
{
    int gid = blockIdx.x * 256 + threadIdx.x;   // 0..65535
    int t = gid >> 5, i = gid & 31;
    double invf = pow(10000.0, -(double)i / 32.0);
    double ang  = (double)t * invf;
    tab[gid] = make_float2((float)cos(ang), (float)sin(ang));
}

// ---------------------------------------------------------------------------
// Kernel 1: weight prep. fp32 W rows (2560: Wq|Wk|Wv|Wo) -> fp16 hi/lo planes.
// Chunk idx = (nb*32+kb)*512 + (nl>>4)*64 + k8*16 + (nl&15)
// holds W[nb*128+nl][kb*32+k8*8 .. +8].
// ---------------------------------------------------------------------------
__global__ __launch_bounds__(256) void prep_w_kernel(
    const float* __restrict__ Wq, const float* __restrict__ Wk,
    const float* __restrict__ Wv, const float* __restrict__ Wo,
    _Float16* __restrict__ Whi, _Float16* __restrict__ Wlo)
{
    int c = blockIdx.x * 256 + threadIdx.x;       // 0..327679
    int k8 = c & 3, kb = (c >> 2) & 31, nl = (c >> 7) & 127, nb = c >> 14;
    int n = nb * 128 + nl, k = kb * 32 + k8 * 8;
    const float* src;
    if (n < 1024)      src = Wq + (size_t)n * 1024;
    else if (n < 1280) src = Wk + (size_t)(n - 1024) * 1024;
    else if (n < 1536) src = Wv + (size_t)(n - 1280) * 1024;
    else               src = Wo + (size_t)(n - 1536) * 1024;
    float4 f0 = *(const float4*)(src + k);
    float4 f1 = *(const float4*)(src + k + 4);
    float xs[8] = {f0.x, f0.y, f0.z, f0.w, f1.x, f1.y, f1.z, f1.w};
    half8_t hi, lo;
#pragma unroll
    for (int j = 0; j < 8; ++j) {
        _Float16 h = (_Float16)xs[j];
        hi[j] = h;
        lo[j] = (_Float16)(xs[j] - (float)h);
    }
    size_t idx = (size_t)(nb * 32 + kb) * 512 + (nl >> 4) * 64 + k8 * 16 + (nl & 15);
    *(half8_t*)&Whi[idx * 8] = hi;
    *(half8_t*)&Wlo[idx * 8] = lo;
}

// ---------------------------------------------------------------------------
// Kernel 2: A prep: hs fp32 [4096 x 1024] -> fp16 chunks, same order as W.
// ---------------------------------------------------------------------------
__global__ __launch_bounds__(256) void prep_a_kernel(
    const float* __restrict__ hs, _Float16* __restrict__ Ah)
{
    int gid = blockIdx.x * 256 + threadIdx.x;    // 0..524287
    int k8 = gid & 3, kb = (gid >> 2) & 31, ml = (gid >> 7) & 127, mb = gid >> 14;
    const float* src = hs + (size_t)(mb * 128 + ml) * 1024 + kb * 32 + k8 * 8;
    float4 f0 = *(const float4*)src;
    float4 f1 = *(const float4*)(src + 4);
    half8_t hv;
    hv[0] = (_Float16)f0.x; hv[1] = (_Float16)f0.y;
    hv[2] = (_Float16)f0.z; hv[3] = (_Float16)f0.w;
    hv[4] = (_Float16)f1.x; hv[5] = (_Float16)f1.y;
    hv[6] = (_Float16)f1.z; hv[7] = (_Float16)f1.w;
    size_t idx = (size_t)(mb * 32 + kb) * 512 + (ml >> 4) * 64 + k8 * 16 + (ml & 15);
    *(half8_t*)&Ah[idx * 8] = hv;
}

// ---------------------------------------------------------------------------
// Kernel 3: 2-pass MFMA GEMM, all-DMA staging. C = A @ (Whi+Wlo)^T + bias.
// 128x64 tile, BK=32, dbuf, 4 waves as 2x2. Unchanged.
// ---------------------------------------------------------------------------
template <int MODE>
__global__ __launch_bounds__(256, 3) void gemm2p_kernel(
    const _Float16* __restrict__ Ah,
    const _Float16* __restrict__ Whi, const _Float16* __restrict__ Wlo,
    int nj0,
    const float* __restrict__ bq, const float* __restrict__ bk,
    const float* __restrict__ bv,
    float* __restrict__ o0, float* __restrict__ o1, float* __restrict__ o2)
{
    __shared__ _Float16 sA [2][4096];
    __shared__ _Float16 sBh[2][2048];
    __shared__ _Float16 sBl[2][2048];

    const int tid  = threadIdx.x;
    const int w    = tid >> 6, lane = tid & 63;
    const int quad = lane >> 4, l15 = lane & 15;
    const int wm = w >> 1, wn = w & 1;
    const int mb   = blockIdx.y;
    const int nblk = blockIdx.x;
    const int nj   = nj0 + nblk;

    const _Float16* AB   = Ah  + (size_t)mb * 32 * 4096;
    const size_t woff = (size_t)(nj >> 1) * 32 * 4096 + (size_t)(nj & 1) * 2048;
    const _Float16* WhiB = Whi + woff;
    const _Float16* WloB = Wlo + woff;

    f32x4 acc[4][2];
#pragma unroll
    for (int mt = 0; mt < 4; ++mt)
#pragma unroll
        for (int nt = 0; nt < 2; ++nt) {
            f32x4 z = {0.f, 0.f, 0.f, 0.f};
            acc[mt][nt] = z;
        }

#define GEMM_STAGE(buf, kbl)                                                  \
    {                                                                         \
        const _Float16* ga = AB   + (size_t)(kbl) * 4096;                     \
        const _Float16* gh = WhiB + (size_t)(kbl) * 4096;                     \
        const _Float16* gl = WloB + (size_t)(kbl) * 4096;                     \
        int cb = w * 64;                                                      \
        async_copy16(&sA [buf][cb * 8],         ga + (size_t)(cb + lane) * 8);        \
        async_copy16(&sA [buf][(cb + 256) * 8], ga + (size_t)(cb + 256 + lane) * 8);  \
        async_copy16(&sBh[buf][cb * 8],         gh + (size_t)(cb + lane) * 8);        \
        async_copy16(&sBl[buf][cb * 8],         gl + (size_t)(cb + lane) * 8);        \
    }

    GEMM_STAGE(0, 0);
    __syncthreads();

    for (int kb = 0; kb < 32; ++kb) {
        const int cur = kb & 1;
        if (kb + 1 < 32) { GEMM_STAGE(cur ^ 1, kb + 1); }

        half8_t af[4], bf[2], blv[2];
#pragma unroll
        for (int mt = 0; mt < 4; ++mt)
            af[mt] = *(const half8_t*)&sA[cur][(((wm * 4 + mt) * 64) + lane) * 8];
#pragma unroll
        for (int nt = 0; nt < 2; ++nt) {
            bf[nt]  = *(const half8_t*)&sBh[cur][(((wn * 2 + nt) * 64) + lane) * 8];
            blv[nt] = *(const half8_t*)&sBl[cur][(((wn * 2 + nt) * 64) + lane) * 8];
        }
#pragma unroll
        for (int mt = 0; mt < 4; ++mt)
#pragma unroll
            for (int nt = 0; nt < 2; ++nt) {
                acc[mt][nt] = __builtin_amdgcn_mfma_f32_16x16x32_f16(af[mt], bf[nt],  acc[mt][nt], 0, 0, 0);
                acc[mt][nt] = __builtin_amdgcn_mfma_f32_16x16x32_f16(af[mt], blv[nt], acc[mt][nt], 0, 0, 0);
            }
        __syncthreads();
    }

    const int m0 = mb * 128;
    if constexpr (MODE == 0) {
        int nreg = nj * 64;
        const float* bias; float* outp; int nh2, nbl;
        if (nreg < 1024)      { bias = bq; outp = o0; nh2 = NH;  nbl = nreg; }
        else if (nreg < 1280) { bias = bk; outp = o1; nh2 = NKV; nbl = nreg - 1024; }
        else                  { bias = bv; outp = o2; nh2 = NKV; nbl = nreg - 1280; }
        int hh = nbl >> 6;
#pragma unroll
        for (int mt = 0; mt < 4; ++mt)
#pragma unroll
            for (int r = 0; r < 4; ++r) {
                int m  = m0 + wm * 64 + mt * 16 + quad * 4 + r;
                int b_ = m >> 11, t_ = m & 2047;
                float* cp = outp + (((size_t)(b_ * nh2 + hh)) * T_ + t_) * 64;
#pragma unroll
                for (int nt = 0; nt < 2; ++nt) {
                    int dd = wn * 32 + nt * 16 + l15;
                    cp[dd] = acc[mt][nt][r] + bias[hh * 64 + dd];
                }
            }
    } else {
        int n0 = nblk * 64 + wn * 32;
#pragma unroll
        for (int mt = 0; mt < 4; ++mt)
#pragma unroll
            for (int r = 0; r < 4; ++r) {
                int m = m0 + wm * 64 + mt * 16 + quad * 4 + r;
#pragma unroll
                for (int nt = 0; nt < 2; ++nt) {
                    int n = n0 + nt * 16 + l15;
                    o0[(size_t)m * 1024 + n] = acc[mt][nt][r] + bq[n];
                }
            }
    }
#undef GEMM_STAGE
}

// ---------------------------------------------------------------------------
// Kernel 4: RoPE via table, fp32 -> fp16 (q pre-scaled by 0.125).
// ---------------------------------------------------------------------------
__global__ __launch_bounds__(256) void rope_half_kernel(
    const float* __restrict__ qf, const float* __restrict__ kf,
    const float2* __restrict__ tab,
    _Float16* __restrict__ qh, _Float16* __restrict__ kh)
{
    int gid = blockIdx.x * 256 + threadIdx.x;
    int i   = gid & 31;
    int row = gid >> 5;
    const float* src; _Float16* dst; int t; float sc;
    if (row < B_ * NH * T_) {
        src = qf + (size_t)row * 64; dst = qh + (size_t)row * 64;
        t = row & (T_ - 1); sc = 0.125f;
    } else {
        int r = row - B_ * NH * T_;
        src = kf + (size_t)r * 64; dst = kh + (size_t)r * 64;
        t = r & (T_ - 1); sc = 1.0f;
    }
    float2 cs = tab[t * 32 + i];
    float c = cs.x, s = cs.y;
    float x0 = src[i], x1 = src[i + 32];
    float xe = src[2 * i], xo = src[2 * i + 1];
    dst[i]      = (_Float16)((x0 * c - xo * s) * sc);
    dst[i + 32] = (_Float16)((x1 * c + xe * s) * sc);
}

// ---------------------------------------------------------------------------
// Kernel 5: V transpose + interleave. vf fp32 [b,hkv,t,d] -> vth fp16 units:
// unit gid = (bhk*16 + kt2)*1024 + c, c: l15=c&15, quad=(c>>4)&3, dt=(c>>6)&3,
// u=c>>8. 8 halves = V^T[d=16dt+l15][keys kt2*128+32u+4quad+{0..3}] then
// [keys +16+{0..3}]. Linear DMA source + conflict-free b128 frag reads in attn.
// ---------------------------------------------------------------------------
__global__ __launch_bounds__(256) void vtrans_kernel(
    const float* __restrict__ vf, _Float16* __restrict__ vth)
{
    int gid = blockIdx.x * 256 + threadIdx.x;    // 0..131071
    int c    = gid & 1023;
    int kt2  = (gid >> 10) & 15;
    int bhk  = gid >> 14;
    int l15  = c & 15, quad = (c >> 4) & 3, dt = (c >> 6) & 3, u = c >> 8;
    int d    = dt * 16 + l15;
    int key0 = kt2 * 128 + u * 32 + quad * 4;
    const float* src = vf + (size_t)bhk * T_ * 64 + d;
    half8_t hv;
#pragma unroll
    for (int j = 0; j < 4; ++j)
        hv[j] = (_Float16)src[(size_t)(key0 + j) * 64];
#pragma unroll
    for (int j = 0; j < 4; ++j)
        hv[4 + j] = (_Float16)src[(size_t)(key0 + 16 + j) * 64];
    *(half8_t*)&vth[(size_t)gid * 8] = hv;
}

// ---------------------------------------------------------------------------
// Kernel 6: flash attention, 128 q/block, 32 q/wave, KVBLK=128.
// S^T = K Q^T -> exp() -> P register-direct into 16x16x16 PV MFMAs.
// Counted-vmcnt pipeline (vmcnt(8) steady state), raw barriers, no setprio.
// K LDS chunk kr*512 + t*64 + kq*16 + kl <-> K[key=16t+kl][d=8*(kr*4+kq)..+8]
// V LDS chunk (u*4+dt)*64 + lane (interleaved, see vtrans) -- both frag
// read classes are wave-contiguous 1KiB ds_read_b128 (conflict-free).
// Epilogue: fp16 stores into the (ml>>4, k8, ml&15) ctx chunk order.
// ---------------------------------------------------------------------------
__global__ __launch_bounds__(256, 2) void attn_kernel(
    const _Float16* __restrict__ qh, const _Float16* __restrict__ kh,
    const _Float16* __restrict__ vth, _Float16* __restrict__ ctx_h)
{
    __shared__ _Float16 Ks[2][8192];
    __shared__ _Float16 Vs[2][8192];

    const int qt = blockIdx.x;          // 0..15 (128-q tiles)
    const int bh = blockIdx.y;          // 0..31
    const int b  = bh >> 4, h = bh & 15, hk = h >> 2;
    const int tid  = threadIdx.x;
    const int w    = tid >> 6;
    const int lane = tid & 63;
    const int quad = lane >> 4, l15 = lane & 15;

    // Q B-frags for 2 strips of 16 q-rows (q pre-scaled by 0.125 at rope)
    half8_t aq0[2], aq1[2];
#pragma unroll
    for (int s = 0; s < 2; ++s) {
        const _Float16* Qb = qh +
            ((size_t)(b * NH + h) * T_ + qt * 128 + w * 32 + s * 16 + l15) * 64 + quad * 8;
        aq0[s] = *(const half8_t*)(Qb);
        aq1[s] = *(const half8_t*)(Qb + 32);
    }
    // Force Q loads resolved here -> no compiler vmcnt waits inside the loop.
    asm volatile("" :: "v"(aq0[0]), "v"(aq0[1]), "v"(aq1[0]), "v"(aq1[1]));

    const _Float16* Kb = kh  + (size_t)(b * NKV + hk) * (T_ * 64);
    const _Float16* Vb = vth + (size_t)(b * NKV + hk) * (64 * T_);

    // Stage one 128-key tile-pair: K 1024 chunks + V 1024 chunks, 8 DMA/thread.
#define ATTN_STAGE(buf, ktile)                                                \
    {                                                                         \
        _Float16* kd = &Ks[buf][0];                                           \
        _Float16* vd = &Vs[buf][0];                                           \
        _Pragma("unroll")                                                     \
        for (int p = 0; p < 4; ++p) {                                         \
            int cb = p * 256 + w * 64;                                        \
            int c  = cb + lane;                                               \
            int kl = c & 15, kq = (c >> 4) & 3, ktt = (c >> 6) & 7, kr = c >> 9; \
            const _Float16* kg = Kb + ((size_t)((ktile) * 128 + ktt * 16 + kl)) * 64 + (kr * 4 + kq) * 8; \
            const _Float16* vg = Vb + ((size_t)(ktile) * 1024 + c) * 8;       \
            async_copy16(kd + cb * 8, kg);                                    \
            async_copy16(vd + cb * 8, vg);                                    \
        }                                                                     \
    }

    float l_i[2] = {0.0f, 0.0f};
    f32x4 o_acc[2][4];
#pragma unroll
    for (int s = 0; s < 2; ++s)
#pragma unroll
        for (int dt = 0; dt < 4; ++dt) { f32x4 z = {0.f,0.f,0.f,0.f}; o_acc[s][dt] = z; }

    ATTN_STAGE(0, 0);

    for (int kt = 0; kt < T_ / 128; ++kt) {
        const int cur = kt & 1;
        if (kt + 1 < T_ / 128) {
            ATTN_STAGE(cur ^ 1, kt + 1);
            VMCNT(8);           // wait stage(cur) only; stage(next) in flight
        } else {
            VMCNT(0);
        }
        wg_barrier();           // buf[cur] ready across all waves

#pragma unroll
        for (int u = 0; u < 4; ++u) {
            // K frags for t=2u, 2u+1: wave-contiguous 1KiB b128 reads
            half8_t ak0[2], ak1[2];
#pragma unroll
            for (int tt = 0; tt < 2; ++tt) {
                const _Float16* kr_ = &Ks[cur][((2 * u + tt) * 64 + lane) * 8];
                ak0[tt] = *(const half8_t*)(kr_);
                ak1[tt] = *(const half8_t*)(kr_ + 4096);
            }
            // V frags: one b128 per (u,dt) holds both t halves (interleaved)
            half8_t av8[4];
#pragma unroll
            for (int dt = 0; dt < 4; ++dt)
                av8[dt] = *(const half8_t*)&Vs[cur][((u * 4 + dt) * 64 + lane) * 8];

#pragma unroll
            for (int s = 0; s < 2; ++s) {
#pragma unroll
                for (int tt = 0; tt < 2; ++tt) {
                    f32x4 z = {0.f,0.f,0.f,0.f};
                    z = __builtin_amdgcn_mfma_f32_16x16x32_f16(ak0[tt], aq0[s], z, 0, 0, 0);
                    f32x4 sv = __builtin_amdgcn_mfma_f32_16x16x32_f16(ak1[tt], aq1[s], z, 0, 0, 0);
                    float p0 = __expf(sv[0]);
                    float p1 = __expf(sv[1]);
                    float p2 = __expf(sv[2]);
                    float p3 = __expf(sv[3]);
                    l_i[s] += (p0 + p1) + (p2 + p3);
                    half4_t pb;
                    pb[0] = (_Float16)p0; pb[1] = (_Float16)p1;
                    pb[2] = (_Float16)p2; pb[3] = (_Float16)p3;
#pragma unroll
                    for (int dt = 0; dt < 4; ++dt) {
                        half4_t a = tt
                            ? __builtin_shufflevector(av8[dt], av8[dt], 4, 5, 6, 7)
                            : __builtin_shufflevector(av8[dt], av8[dt], 0, 1, 2, 3);
                        o_acc[s][dt] = __builtin_amdgcn_mfma_f32_16x16x16f16(
                            a, pb, o_acc[s][dt], 0, 0, 0);
                    }
                }
            }
        }
        LGKMCNT0();             // all LDS reads of buf[cur] retired
        wg_barrier();           // safe for next iter's DMA to overwrite
    }

    // epilogue: reduce l across quads (lane bits 4,5), normalize, store fp16
    // into ctx chunks: idx = (mb*32+kb)*512 + (ml>>4)*64 + k8*16 + (ml&15)
    const int mb = b * 16 + qt;
#pragma unroll
    for (int s = 0; s < 2; ++s) {
        float l = l_i[s];
        l += __shfl_xor(l, 16);
        l += __shfl_xor(l, 32);
        float inv = 1.0f / l;
        // ml = w*32 + s*16 + l15  ->  ml>>4 = 2w+s, ml&15 = l15
#pragma unroll
        for (int dt = 0; dt < 4; ++dt)
#pragma unroll
            for (int r = 0; r < 4; ++r) {
                int d   = 16 * dt + 4 * quad + r;
                int kb_ = 2 * h + (d >> 5);
                int k8  = (d >> 3) & 3;
                int j   = d & 7;
                size_t idx = (size_t)(mb * 32 + kb_) * 512 + (w * 2 + s) * 64 + k8 * 16 + l15;
                ctx_h[idx * 8 + j] = (_Float16)(o_acc[s][dt][r] * inv);
            }
    }
#undef ATTN_STAGE
}

// ---------------------------------------------------------------------------
extern "C" void kernel_launch(void* const* d_in, const int* in_sizes, int n_in,
                              void* d_out, int out_size, void* d_ws, size_t ws_size,
                              hipStream_t stream)
{
    const float* hs = (const float*)d_in[0];
    const float* Wq = (const float*)d_in[1];
    const float* bq = (const float*)d_in[2];
    const float* Wk = (const float*)d_in[3];
    const float* bk = (const float*)d_in[4];
    const float* Wv = (const float*)d_in[5];
    const float* bv = (const float*)d_in[6];
    const float* Wo = (const float*)d_in[7];
    const float* bo = (const float*)d_in[8];
    float* out = (float*)d_out;

    const size_t MB = 1024 * 1024;
    if (ws_size < 46 * MB) return;

    char* w = (char*)d_ws;
    _Float16* Whi  = (_Float16*)(w);             // 5 MB  [0,5)
    _Float16* Wlo  = (_Float16*)(w + 5 * MB);    // 5 MB  [5,10)
    float*    qf32 = (float*)(w + 10 * MB);      // 16 MB [10,26)
    float*    kf32 = (float*)(w + 26 * MB);      // 4 MB  [26,30)
    float*    vf32 = (float*)(w + 30 * MB);      // 4 MB  [30,34)
    _Float16* qh   = (_Float16*)(w + 34 * MB);   // 8 MB  [34,42)
    _Float16* kh   = (_Float16*)(w + 42 * MB);   // 2 MB  [42,44)
    _Float16* vth  = (_Float16*)(w + 44 * MB);   // 2 MB  [44,46)
    // aliases (lifetimes disjoint):
    _Float16* hs_h  = qh;                        // dead once rope writes qh
    float2*   tab   = (float2*)vth;              // dead once vtrans writes vth
    _Float16* ctx_h = (_Float16*)qf32;           // qf32 dead after rope

    tab_kernel<<<256, 256, 0, stream>>>(tab);
    prep_w_kernel<<<1280, 256, 0, stream>>>(Wq, Wk, Wv, Wo, Whi, Wlo);
    prep_a_kernel<<<2048, 256, 0, stream>>>(hs, hs_h);
    gemm2p_kernel<0><<<dim3(24, 32), 256, 0, stream>>>(
        hs_h, Whi, Wlo, 0, bq, bk, bv, qf32, kf32, vf32);
    rope_half_kernel<<<(B_ * (NH + NKV) * T_ * 32) / 256, 256, 0, stream>>>(
        qf32, kf32, tab, qh, kh);
    vtrans_kernel<<<512, 256, 0, stream>>>(vf32, vth);
    attn_kernel<<<dim3(T_ / 128, B_ * NH), 256, 0, stream>>>(qh, kh, vth, ctx_h);
    gemm2p_kernel<1><<<dim3(16, 32), 256, 0, stream>>>(
        ctx_h, Whi, Wlo, 24, bo, nullptr, nullptr, out, nullptr, nullptr);
}

// Round 6
// 199.549 us; speedup vs baseline: 1.2507x; 1.0348x over previous
//
#include <hip/hip_runtime.h>
#include <math.h>

// GQA block. Round 10: GEMM locality + pipeline pass (attn untouched after
// its r9 win: conflicts 4.2M->0, 67->51us).
// (a) GEMM grid transposed (x=mb, y=nj): consecutive blocks share the W
//     panel -> per-XCD L2 reuse of the 20MB hi/lo planes (was: shared the
//     256KB A panel and re-pulled W from L3 per mb).
// (b) GEMM uses the attn-proven counted-vmcnt pipeline: stage(next),
//     vmcnt(4), raw barrier, compute, lgkmcnt(0), raw barrier. No vmcnt(0)
//     drain in steady state.
// (c) tab+prep_w+prep_a fused into one kernel (launch overhead; tab's
//     double-precision VALU hides under the memory-bound preps).
// Shapes: B=2, T=2048, DIM=1024, H=16, HKV=4, HD=64.

#define B_   2
#define T_   2048
#define DIM_ 1024
#define NH   16
#define NKV  4
#define HD_  64
#define BT_  (B_ * T_)

typedef _Float16 half8_t __attribute__((ext_vector_type(8)));
typedef _Float16 half4_t __attribute__((ext_vector_type(4)));
typedef float    f32x4   __attribute__((ext_vector_type(4)));

__device__ __forceinline__ void async_copy16(_Float16* lds, const _Float16* g) {
    __builtin_amdgcn_global_load_lds(
        (const __attribute__((address_space(1))) void*)g,
        (__attribute__((address_space(3))) void*)lds, 16, 0, 0);
}

#define VMCNT(n) asm volatile("s_waitcnt vmcnt(" #n ")" ::: "memory")
#define LGKMCNT0() asm volatile("s_waitcnt lgkmcnt(0)" ::: "memory")

__device__ __forceinline__ void wg_barrier() {
    asm volatile("" ::: "memory");
    __builtin_amdgcn_s_barrier();
    asm volatile("" ::: "memory");
}

// ---------------------------------------------------------------------------
// Kernel 1: fused prep. Block ranges:
//   [0,256):     RoPE sincos table tab[t*32+i]
//   [256,1536):  weight prep  fp32 W rows (2560: Wq|Wk|Wv|Wo) -> fp16 hi/lo
//   [1536,3584): A prep       hs fp32 [4096x1024] -> fp16 chunks
// Chunk idx = (nb*32+kb)*512 + (nl>>4)*64 + k8*16 + (nl&15)
// holds X[nb*128+nl][kb*32+k8*8 .. +8].
// ---------------------------------------------------------------------------
__global__ __launch_bounds__(256) void prep_all_kernel(
    float2* __restrict__ tab,
    const float* __restrict__ Wq, const float* __restrict__ Wk,
    const float* __restrict__ Wv, const float* __restrict__ Wo,
    _Float16* __restrict__ Whi, _Float16* __restrict__ Wlo,
    const float* __restrict__ hs, _Float16* __restrict__ Ah)
{
    const int bid = blockIdx.x;
    const int tid = threadIdx.x;
    if (bid < 256) {
        int gid = bid * 256 + tid;                // 0..65535
        int t = gid >> 5, i = gid & 31;
        double invf = pow(10000.0, -(double)i / 32.0);
        double ang  = (double)t * invf;
        tab[gid] = make_float2((float)cos(ang), (float)sin(ang));
    } else if (bid < 1536) {
        int c = (bid - 256) * 256 + tid;          // 0..327679
        int k8 = c & 3, kb = (c >> 2) & 31, nl = (c >> 7) & 127, nb = c >> 14;
        int n = nb * 128 + nl, k = kb * 32 + k8 * 8;
        const float* src;
        if (n < 1024)      src = Wq + (size_t)n * 1024;
        else if (n < 1280) src = Wk + (size_t)(n - 1024) * 1024;
        else if (n < 1536) src = Wv + (size_t)(n - 1280) * 1024;
        else               src = Wo + (size_t)(n - 1536) * 1024;
        float4 f0 = *(const float4*)(src + k);
        float4 f1 = *(const float4*)(src + k + 4);
        float xs[8] = {f0.x, f0.y, f0.z, f0.w, f1.x, f1.y, f1.z, f1.w};
        half8_t hi, lo;
#pragma unroll
        for (int j = 0; j < 8; ++j) {
            _Float16 h = (_Float16)xs[j];
            hi[j] = h;
            lo[j] = (_Float16)(xs[j] - (float)h);
        }
        size_t idx = (size_t)(nb * 32 + kb) * 512 + (nl >> 4) * 64 + k8 * 16 + (nl & 15);
        *(half8_t*)&Whi[idx * 8] = hi;
        *(half8_t*)&Wlo[idx * 8] = lo;
    } else {
        int gid = (bid - 1536) * 256 + tid;       // 0..524287
        int k8 = gid & 3, kb = (gid >> 2) & 31, ml = (gid >> 7) & 127, mb = gid >> 14;
        const float* src = hs + (size_t)(mb * 128 + ml) * 1024 + kb * 32 + k8 * 8;
        float4 f0 = *(const float4*)src;
        float4 f1 = *(const float4*)(src + 4);
        half8_t hv;
        hv[0] = (_Float16)f0.x; hv[1] = (_Float16)f0.y;
        hv[2] = (_Float16)f0.z; hv[3] = (_Float16)f0.w;
        hv[4] = (_Float16)f1.x; hv[5] = (_Float16)f1.y;
        hv[6] = (_Float16)f1.z; hv[7] = (_Float16)f1.w;
        size_t idx = (size_t)(mb * 32 + kb) * 512 + (ml >> 4) * 64 + k8 * 16 + (ml & 15);
        *(half8_t*)&Ah[idx * 8] = hv;
    }
}

// ---------------------------------------------------------------------------
// Kernel 3: 2-pass MFMA GEMM, all-DMA staging. C = A @ (Whi+Wlo)^T + bias.
// 128x64 tile, BK=32, dbuf, 4 waves as 2x2.
// Grid (mb, nj-rel): x=mb so consecutive blocks share the W panel (L2 reuse).
// Counted-vmcnt pipeline (vmcnt(4) steady state), raw barriers.
// MODE 0: QKV epilogue (scatter fp32 [b,h,t,d]). MODE 1: row-major fp32 out.
// ---------------------------------------------------------------------------
template <int MODE>
__global__ __launch_bounds__(256, 3) void gemm2p_kernel(
    const _Float16* __restrict__ Ah,
    const _Float16* __restrict__ Whi, const _Float16* __restrict__ Wlo,
    int nj0,
    const float* __restrict__ bq, const float* __restrict__ bk,
    const float* __restrict__ bv,
    float* __restrict__ o0, float* __restrict__ o1, float* __restrict__ o2)
{
    __shared__ _Float16 sA [2][4096];
    __shared__ _Float16 sBh[2][2048];
    __shared__ _Float16 sBl[2][2048];

    const int tid  = threadIdx.x;
    const int w    = tid >> 6, lane = tid & 63;
    const int quad = lane >> 4, l15 = lane & 15;
    const int wm = w >> 1, wn = w & 1;
    const int mb   = blockIdx.x;          // transposed: x = row tile
    const int nblk = blockIdx.y;
    const int nj   = nj0 + nblk;

    const _Float16* AB   = Ah  + (size_t)mb * 32 * 4096;
    const size_t woff = (size_t)(nj >> 1) * 32 * 4096 + (size_t)(nj & 1) * 2048;
    const _Float16* WhiB = Whi + woff;
    const _Float16* WloB = Wlo + woff;

    f32x4 acc[4][2];
#pragma unroll
    for (int mt = 0; mt < 4; ++mt)
#pragma unroll
        for (int nt = 0; nt < 2; ++nt) {
            f32x4 z = {0.f, 0.f, 0.f, 0.f};
            acc[mt][nt] = z;
        }

#define GEMM_STAGE(buf, kbl)                                                  \
    {                                                                         \
        const _Float16* ga = AB   + (size_t)(kbl) * 4096;                     \
        const _Float16* gh = WhiB + (size_t)(kbl) * 4096;                     \
        const _Float16* gl = WloB + (size_t)(kbl) * 4096;                     \
        int cb = w * 64;                                                      \
        async_copy16(&sA [buf][cb * 8],         ga + (size_t)(cb + lane) * 8);        \
        async_copy16(&sA [buf][(cb + 256) * 8], ga + (size_t)(cb + 256 + lane) * 8);  \
        async_copy16(&sBh[buf][cb * 8],         gh + (size_t)(cb + lane) * 8);        \
        async_copy16(&sBl[buf][cb * 8],         gl + (size_t)(cb + lane) * 8);        \
    }

    GEMM_STAGE(0, 0);

    for (int kb = 0; kb < 32; ++kb) {
        const int cur = kb & 1;
        if (kb + 1 < 32) {
            GEMM_STAGE(cur ^ 1, kb + 1);
            VMCNT(4);           // stage(cur) done; stage(next) in flight
        } else {
            VMCNT(0);
        }
        wg_barrier();

        half8_t af[4], bf[2], blv[2];
#pragma unroll
        for (int mt = 0; mt < 4; ++mt)
            af[mt] = *(const half8_t*)&sA[cur][(((wm * 4 + mt) * 64) + lane) * 8];
#pragma unroll
        for (int nt = 0; nt < 2; ++nt) {
            bf[nt]  = *(const half8_t*)&sBh[cur][(((wn * 2 + nt) * 64) + lane) * 8];
            blv[nt] = *(const half8_t*)&sBl[cur][(((wn * 2 + nt) * 64) + lane) * 8];
        }
#pragma unroll
        for (int mt = 0; mt < 4; ++mt)
#pragma unroll
            for (int nt = 0; nt < 2; ++nt) {
                acc[mt][nt] = __builtin_amdgcn_mfma_f32_16x16x32_f16(af[mt], bf[nt],  acc[mt][nt], 0, 0, 0);
                acc[mt][nt] = __builtin_amdgcn_mfma_f32_16x16x32_f16(af[mt], blv[nt], acc[mt][nt], 0, 0, 0);
            }
        LGKMCNT0();             // LDS reads of buf[cur] retired
        wg_barrier();           // safe for next iter's DMA to overwrite
    }

    const int m0 = mb * 128;
    if constexpr (MODE == 0) {
        int nreg = nj * 64;
        const float* bias; float* outp; int nh2, nbl;
        if (nreg < 1024)      { bias = bq; outp = o0; nh2 = NH;  nbl = nreg; }
        else if (nreg < 1280) { bias = bk; outp = o1; nh2 = NKV; nbl = nreg - 1024; }
        else                  { bias = bv; outp = o2; nh2 = NKV; nbl = nreg - 1280; }
        int hh = nbl >> 6;
#pragma unroll
        for (int mt = 0; mt < 4; ++mt)
#pragma unroll
            for (int r = 0; r < 4; ++r) {
                int m  = m0 + wm * 64 + mt * 16 + quad * 4 + r;
                int b_ = m >> 11, t_ = m & 2047;
                float* cp = outp + (((size_t)(b_ * nh2 + hh)) * T_ + t_) * 64;
#pragma unroll
                for (int nt = 0; nt < 2; ++nt) {
                    int dd = wn * 32 + nt * 16 + l15;
                    cp[dd] = acc[mt][nt][r] + bias[hh * 64 + dd];
                }
            }
    } else {
        int n0 = nblk * 64 + wn * 32;
#pragma unroll
        for (int mt = 0; mt < 4; ++mt)
#pragma unroll
            for (int r = 0; r < 4; ++r) {
                int m = m0 + wm * 64 + mt * 16 + quad * 4 + r;
#pragma unroll
                for (int nt = 0; nt < 2; ++nt) {
                    int n = n0 + nt * 16 + l15;
                    o0[(size_t)m * 1024 + n] = acc[mt][nt][r] + bq[n];
                }
            }
    }
#undef GEMM_STAGE
}

// ---------------------------------------------------------------------------
// Kernel 4: RoPE via table, fp32 -> fp16 (q pre-scaled by 0.125).
// ---------------------------------------------------------------------------
__global__ __launch_bounds__(256) void rope_half_kernel(
    const float* __restrict__ qf, const float* __restrict__ kf,
    const float2* __restrict__ tab,
    _Float16* __restrict__ qh, _Float16* __restrict__ kh)
{
    int gid = blockIdx.x * 256 + threadIdx.x;
    int i   = gid & 31;
    int row = gid >> 5;
    const float* src; _Float16* dst; int t; float sc;
    if (row < B_ * NH * T_) {
        src = qf + (size_t)row * 64; dst = qh + (size_t)row * 64;
        t = row & (T_ - 1); sc = 0.125f;
    } else {
        int r = row - B_ * NH * T_;
        src = kf + (size_t)r * 64; dst = kh + (size_t)r * 64;
        t = r & (T_ - 1); sc = 1.0f;
    }
    float2 cs = tab[t * 32 + i];
    float c = cs.x, s = cs.y;
    float x0 = src[i], x1 = src[i + 32];
    float xe = src[2 * i], xo = src[2 * i + 1];
    dst[i]      = (_Float16)((x0 * c - xo * s) * sc);
    dst[i + 32] = (_Float16)((x1 * c + xe * s) * sc);
}

// ---------------------------------------------------------------------------
// Kernel 5: V transpose + interleave. vf fp32 [b,hkv,t,d] -> vth fp16 units:
// unit gid = (bhk*16 + kt2)*1024 + c, c: l15=c&15, quad=(c>>4)&3, dt=(c>>6)&3,
// u=c>>8. 8 halves = V^T[d=16dt+l15][keys kt2*128+32u+4quad+{0..3}] then
// [keys +16+{0..3}]. Linear DMA source + conflict-free b128 frag reads in attn.
// ---------------------------------------------------------------------------
__global__ __launch_bounds__(256) void vtrans_kernel(
    const float* __restrict__ vf, _Float16* __restrict__ vth)
{
    int gid = blockIdx.x * 256 + threadIdx.x;    // 0..131071
    int c    = gid & 1023;
    int kt2  = (gid >> 10) & 15;
    int bhk  = gid >> 14;
    int l15  = c & 15, quad = (c >> 4) & 3, dt = (c >> 6) & 3, u = c >> 8;
    int d    = dt * 16 + l15;
    int key0 = kt2 * 128 + u * 32 + quad * 4;
    const float* src = vf + (size_t)bhk * T_ * 64 + d;
    half8_t hv;
#pragma unroll
    for (int j = 0; j < 4; ++j)
        hv[j] = (_Float16)src[(size_t)(key0 + j) * 64];
#pragma unroll
    for (int j = 0; j < 4; ++j)
        hv[4 + j] = (_Float16)src[(size_t)(key0 + 16 + j) * 64];
    *(half8_t*)&vth[(size_t)gid * 8] = hv;
}

// ---------------------------------------------------------------------------
// Kernel 6: flash attention, 128 q/block, 32 q/wave, KVBLK=128. Unchanged
// from round 9 (51.4us, 0 bank conflicts, MfmaUtil 41%).
// ---------------------------------------------------------------------------
__global__ __launch_bounds__(256, 2) void attn_kernel(
    const _Float16* __restrict__ qh, const _Float16* __restrict__ kh,
    const _Float16* __restrict__ vth, _Float16* __restrict__ ctx_h)
{
    __shared__ _Float16 Ks[2][8192];
    __shared__ _Float16 Vs[2][8192];

    const int qt = blockIdx.x;          // 0..15 (128-q tiles)
    const int bh = blockIdx.y;          // 0..31
    const int b  = bh >> 4, h = bh & 15, hk = h >> 2;
    const int tid  = threadIdx.x;
    const int w    = tid >> 6;
    const int lane = tid & 63;
    const int quad = lane >> 4, l15 = lane & 15;

    // Q B-frags for 2 strips of 16 q-rows (q pre-scaled by 0.125 at rope)
    half8_t aq0[2], aq1[2];
#pragma unroll
    for (int s = 0; s < 2; ++s) {
        const _Float16* Qb = qh +
            ((size_t)(b * NH + h) * T_ + qt * 128 + w * 32 + s * 16 + l15) * 64 + quad * 8;
        aq0[s] = *(const half8_t*)(Qb);
        aq1[s] = *(const half8_t*)(Qb + 32);
    }
    // Force Q loads resolved here -> no compiler vmcnt waits inside the loop.
    asm volatile("" :: "v"(aq0[0]), "v"(aq0[1]), "v"(aq1[0]), "v"(aq1[1]));

    const _Float16* Kb = kh  + (size_t)(b * NKV + hk) * (T_ * 64);
    const _Float16* Vb = vth + (size_t)(b * NKV + hk) * (64 * T_);

    // Stage one 128-key tile-pair: K 1024 chunks + V 1024 chunks, 8 DMA/thread.
#define ATTN_STAGE(buf, ktile)                                                \
    {                                                                         \
        _Float16* kd = &Ks[buf][0];                                           \
        _Float16* vd = &Vs[buf][0];                                           \
        _Pragma("unroll")                                                     \
        for (int p = 0; p < 4; ++p) {                                         \
            int cb = p * 256 + w * 64;                                        \
            int c  = cb + lane;                                               \
            int kl = c & 15, kq = (c >> 4) & 3, ktt = (c >> 6) & 7, kr = c >> 9; \
            const _Float16* kg = Kb + ((size_t)((ktile) * 128 + ktt * 16 + kl)) * 64 + (kr * 4 + kq) * 8; \
            const _Float16* vg = Vb + ((size_t)(ktile) * 1024 + c) * 8;       \
            async_copy16(kd + cb * 8, kg);                                    \
            async_copy16(vd + cb * 8, vg);                                    \
        }                                                                     \
    }

    float l_i[2] = {0.0f, 0.0f};
    f32x4 o_acc[2][4];
#pragma unroll
    for (int s = 0; s < 2; ++s)
#pragma unroll
        for (int dt = 0; dt < 4; ++dt) { f32x4 z = {0.f,0.f,0.f,0.f}; o_acc[s][dt] = z; }

    ATTN_STAGE(0, 0);

    for (int kt = 0; kt < T_ / 128; ++kt) {
        const int cur = kt & 1;
        if (kt + 1 < T_ / 128) {
            ATTN_STAGE(cur ^ 1, kt + 1);
            VMCNT(8);           // wait stage(cur) only; stage(next) in flight
        } else {
            VMCNT(0);
        }
        wg_barrier();           // buf[cur] ready across all waves

#pragma unroll
        for (int u = 0; u < 4; ++u) {
            // K frags for t=2u, 2u+1: wave-contiguous 1KiB b128 reads
            half8_t ak0[2], ak1[2];
#pragma unroll
            for (int tt = 0; tt < 2; ++tt) {
                const _Float16* kr_ = &Ks[cur][((2 * u + tt) * 64 + lane) * 8];
                ak0[tt] = *(const half8_t*)(kr_);
                ak1[tt] = *(const half8_t*)(kr_ + 4096);
            }
            // V frags: one b128 per (u,dt) holds both t halves (interleaved)
            half8_t av8[4];
#pragma unroll
            for (int dt = 0; dt < 4; ++dt)
                av8[dt] = *(const half8_t*)&Vs[cur][((u * 4 + dt) * 64 + lane) * 8];

#pragma unroll
            for (int s = 0; s < 2; ++s) {
#pragma unroll
                for (int tt = 0; tt < 2; ++tt) {
                    f32x4 z = {0.f,0.f,0.f,0.f};
                    z = __builtin_amdgcn_mfma_f32_16x16x32_f16(ak0[tt], aq0[s], z, 0, 0, 0);
                    f32x4 sv = __builtin_amdgcn_mfma_f32_16x16x32_f16(ak1[tt], aq1[s], z, 0, 0, 0);
                    float p0 = __expf(sv[0]);
                    float p1 = __expf(sv[1]);
                    float p2 = __expf(sv[2]);
                    float p3 = __expf(sv[3]);
                    l_i[s] += (p0 + p1) + (p2 + p3);
                    half4_t pb;
                    pb[0] = (_Float16)p0; pb[1] = (_Float16)p1;
                    pb[2] = (_Float16)p2; pb[3] = (_Float16)p3;
#pragma unroll
                    for (int dt = 0; dt < 4; ++dt) {
                        half4_t a = tt
                            ? __builtin_shufflevector(av8[dt], av8[dt], 4, 5, 6, 7)
                            : __builtin_shufflevector(av8[dt], av8[dt], 0, 1, 2, 3);
                        o_acc[s][dt] = __builtin_amdgcn_mfma_f32_16x16x16f16(
                            a, pb, o_acc[s][dt], 0, 0, 0);
                    }
                }
            }
        }
        LGKMCNT0();             // all LDS reads of buf[cur] retired
        wg_barrier();           // safe for next iter's DMA to overwrite
    }

    // epilogue: reduce l across quads (lane bits 4,5), normalize, store fp16
    // into ctx chunks: idx = (mb*32+kb)*512 + (ml>>4)*64 + k8*16 + (ml&15)
    const int mb = b * 16 + qt;
#pragma unroll
    for (int s = 0; s < 2; ++s) {
        float l = l_i[s];
        l += __shfl_xor(l, 16);
        l += __shfl_xor(l, 32);
        float inv = 1.0f / l;
        // ml = w*32 + s*16 + l15  ->  ml>>4 = 2w+s, ml&15 = l15
#pragma unroll
        for (int dt = 0; dt < 4; ++dt)
#pragma unroll
            for (int r = 0; r < 4; ++r) {
                int d   = 16 * dt + 4 * quad + r;
                int kb_ = 2 * h + (d >> 5);
                int k8  = (d >> 3) & 3;
                int j   = d & 7;
                size_t idx = (size_t)(mb * 32 + kb_) * 512 + (w * 2 + s) * 64 + k8 * 16 + l15;
                ctx_h[idx * 8 + j] = (_Float16)(o_acc[s][dt][r] * inv);
            }
    }
#undef ATTN_STAGE
}

// ---------------------------------------------------------------------------
extern "C" void kernel_launch(void* const* d_in, const int* in_sizes, int n_in,
                              void* d_out, int out_size, void* d_ws, size_t ws_size,
                              hipStream_t stream)
{
    const float* hs = (const float*)d_in[0];
    const float* Wq = (const float*)d_in[1];
    const float* bq = (const float*)d_in[2];
    const float* Wk = (const float*)d_in[3];
    const float* bk = (const float*)d_in[4];
    const float* Wv = (const float*)d_in[5];
    const float* bv = (const float*)d_in[6];
    const float* Wo = (const float*)d_in[7];
    const float* bo = (const float*)d_in[8];
    float* out = (float*)d_out;

    const size_t MB = 1024 * 1024;
    if (ws_size < 46 * MB) return;

    char* w = (char*)d_ws;
    _Float16* Whi  = (_Float16*)(w);             // 5 MB  [0,5)
    _Float16* Wlo  = (_Float16*)(w + 5 * MB);    // 5 MB  [5,10)
    float*    qf32 = (float*)(w + 10 * MB);      // 16 MB [10,26)
    float*    kf32 = (float*)(w + 26 * MB);      // 4 MB  [26,30)
    float*    vf32 = (float*)(w + 30 * MB);      // 4 MB  [30,34)
    _Float16* qh   = (_Float16*)(w + 34 * MB);   // 8 MB  [34,42)
    _Float16* kh   = (_Float16*)(w + 42 * MB);   // 2 MB  [42,44)
    _Float16* vth  = (_Float16*)(w + 44 * MB);   // 2 MB  [44,46)
    // aliases (lifetimes disjoint):
    _Float16* hs_h  = qh;                        // dead once rope writes qh
    float2*   tab   = (float2*)vth;              // dead once vtrans writes vth
    _Float16* ctx_h = (_Float16*)qf32;           // qf32 dead after rope

    prep_all_kernel<<<3584, 256, 0, stream>>>(
        tab, Wq, Wk, Wv, Wo, Whi, Wlo, hs, hs_h);
    gemm2p_kernel<0><<<dim3(32, 24), 256, 0, stream>>>(
        hs_h, Whi, Wlo, 0, bq, bk, bv, qf32, kf32, vf32);
    rope_half_kernel<<<(B_ * (NH + NKV) * T_ * 32) / 256, 256, 0, stream>>>(
        qf32, kf32, tab, qh, kh);
    vtrans_kernel<<<512, 256, 0, stream>>>(vf32, vth);
    attn_kernel<<<dim3(T_ / 128, B_ * NH), 256, 0, stream>>>(qh, kh, vth, ctx_h);
    gemm2p_kernel<1><<<dim3(32, 16), 256, 0, stream>>>(
        ctx_h, Whi, Wlo, 24, bo, nullptr, nullptr, out, nullptr, nullptr);
}

// Round 7
// 194.152 us; speedup vs baseline: 1.2854x; 1.0278x over previous
//
#include <hip/hip_runtime.h>
#include <math.h>

// GQA block. Round 11: epilogue-fusion pass (attn untouched, 51us/0 conflicts).
// (a) rope fused into QKV-GEMM epilogue: 128x64 fp32 tile staged in the
//     (union'd) 32KB GEMM LDS, table rotation applied, fp16 stored to qh/kh.
// (b) V blocks store the attn-interleaved vth layout directly from accs
//     (lane (quad,l15) holds exactly one vth unit's 8 keys) -- no LDS.
// (c) rope_half + vtrans kernels deleted (2 launches, 28MB fp32 round-trip).
// (d) workspace re-laid: tab gets own slot (no alias with vth); ctx aliases
//     dead A-chunks. 4 kernel launches total.
// Shapes: B=2, T=2048, DIM=1024, H=16, HKV=4, HD=64.

#define B_   2
#define T_   2048
#define DIM_ 1024
#define NH   16
#define NKV  4
#define HD_  64
#define BT_  (B_ * T_)

typedef _Float16 half8_t __attribute__((ext_vector_type(8)));
typedef _Float16 half4_t __attribute__((ext_vector_type(4)));
typedef float    f32x4   __attribute__((ext_vector_type(4)));

__device__ __forceinline__ void async_copy16(_Float16* lds, const _Float16* g) {
    __builtin_amdgcn_global_load_lds(
        (const __attribute__((address_space(1))) void*)g,
        (__attribute__((address_space(3))) void*)lds, 16, 0, 0);
}

#define VMCNT(n) asm volatile("s_waitcnt vmcnt(" #n ")" ::: "memory")
#define LGKMCNT0() asm volatile("s_waitcnt lgkmcnt(0)" ::: "memory")

__device__ __forceinline__ void wg_barrier() {
    asm volatile("" ::: "memory");
    __builtin_amdgcn_s_barrier();
    asm volatile("" ::: "memory");
}

// ---------------------------------------------------------------------------
// Kernel 1: fused prep. Block ranges:
//   [0,256):     RoPE sincos table tab[t*32+i]
//   [256,1536):  weight prep  fp32 W rows (2560: Wq|Wk|Wv|Wo) -> fp16 hi/lo
//   [1536,3584): A prep       hs fp32 [4096x1024] -> fp16 chunks
// Chunk idx = (nb*32+kb)*512 + (nl>>4)*64 + k8*16 + (nl&15)
// ---------------------------------------------------------------------------
__global__ __launch_bounds__(256) void prep_all_kernel(
    float2* __restrict__ tab,
    const float* __restrict__ Wq, const float* __restrict__ Wk,
    const float* __restrict__ Wv, const float* __restrict__ Wo,
    _Float16* __restrict__ Whi, _Float16* __restrict__ Wlo,
    const float* __restrict__ hs, _Float16* __restrict__ Ah)
{
    const int bid = blockIdx.x;
    const int tid = threadIdx.x;
    if (bid < 256) {
        int gid = bid * 256 + tid;                // 0..65535
        int t = gid >> 5, i = gid & 31;
        double invf = pow(10000.0, -(double)i / 32.0);
        double ang  = (double)t * invf;
        tab[gid] = make_float2((float)cos(ang), (float)sin(ang));
    } else if (bid < 1536) {
        int c = (bid - 256) * 256 + tid;          // 0..327679
        int k8 = c & 3, kb = (c >> 2) & 31, nl = (c >> 7) & 127, nb = c >> 14;
        int n = nb * 128 + nl, k = kb * 32 + k8 * 8;
        const float* src;
        if (n < 1024)      src = Wq + (size_t)n * 1024;
        else if (n < 1280) src = Wk + (size_t)(n - 1024) * 1024;
        else if (n < 1536) src = Wv + (size_t)(n - 1280) * 1024;
        else               src = Wo + (size_t)(n - 1536) * 1024;
        float4 f0 = *(const float4*)(src + k);
        float4 f1 = *(const float4*)(src + k + 4);
        float xs[8] = {f0.x, f0.y, f0.z, f0.w, f1.x, f1.y, f1.z, f1.w};
        half8_t hi, lo;
#pragma unroll
        for (int j = 0; j < 8; ++j) {
            _Float16 h = (_Float16)xs[j];
            hi[j] = h;
            lo[j] = (_Float16)(xs[j] - (float)h);
        }
        size_t idx = (size_t)(nb * 32 + kb) * 512 + (nl >> 4) * 64 + k8 * 16 + (nl & 15);
        *(half8_t*)&Whi[idx * 8] = hi;
        *(half8_t*)&Wlo[idx * 8] = lo;
    } else {
        int gid = (bid - 1536) * 256 + tid;       // 0..524287
        int k8 = gid & 3, kb = (gid >> 2) & 31, ml = (gid >> 7) & 127, mb = gid >> 14;
        const float* src = hs + (size_t)(mb * 128 + ml) * 1024 + kb * 32 + k8 * 8;
        float4 f0 = *(const float4*)src;
        float4 f1 = *(const float4*)(src + 4);
        half8_t hv;
        hv[0] = (_Float16)f0.x; hv[1] = (_Float16)f0.y;
        hv[2] = (_Float16)f0.z; hv[3] = (_Float16)f0.w;
        hv[4] = (_Float16)f1.x; hv[5] = (_Float16)f1.y;
        hv[6] = (_Float16)f1.z; hv[7] = (_Float16)f1.w;
        size_t idx = (size_t)(mb * 32 + kb) * 512 + (ml >> 4) * 64 + k8 * 16 + (ml & 15);
        *(half8_t*)&Ah[idx * 8] = hv;
    }
}

// ---------------------------------------------------------------------------
// Kernel 3: 2-pass MFMA GEMM, all-DMA staging. C = A @ (Whi+Wlo)^T + bias.
// 128x64 tile, BK=32, dbuf, 4 waves as 2x2, counted-vmcnt pipeline.
// MODE 0: fused epilogue -- q/k: LDS-staged rope -> fp16 qh/kh;
//         v: direct interleaved vth stores.  MODE 1: row-major fp32 + bias.
// ---------------------------------------------------------------------------
template <int MODE>
__global__ __launch_bounds__(256, 3) void gemm2p_kernel(
    const _Float16* __restrict__ Ah,
    const _Float16* __restrict__ Whi, const _Float16* __restrict__ Wlo,
    int nj0,
    const float* __restrict__ bq, const float* __restrict__ bk,
    const float* __restrict__ bv,
    const float2* __restrict__ tab,
    float* __restrict__ o0f,
    _Float16* __restrict__ qh, _Float16* __restrict__ kh,
    _Float16* __restrict__ vth)
{
    // 32KB union: staging (sA 16K | sBh 8K | sBl 8K) vs epilogue fp32 tile.
    __shared__ __align__(16) char smem[32768];
    _Float16 (*sA )[4096] = (_Float16(*)[4096])(smem);
    _Float16 (*sBh)[2048] = (_Float16(*)[2048])(smem + 16384);
    _Float16 (*sBl)[2048] = (_Float16(*)[2048])(smem + 24576);

    const int tid  = threadIdx.x;
    const int w    = tid >> 6, lane = tid & 63;
    const int quad = lane >> 4, l15 = lane & 15;
    const int wm = w >> 1, wn = w & 1;
    const int mb   = blockIdx.x;          // x = row tile (W-panel L2 reuse)
    const int nblk = blockIdx.y;
    const int nj   = nj0 + nblk;

    const _Float16* AB   = Ah  + (size_t)mb * 32 * 4096;
    const size_t woff = (size_t)(nj >> 1) * 32 * 4096 + (size_t)(nj & 1) * 2048;
    const _Float16* WhiB = Whi + woff;
    const _Float16* WloB = Wlo + woff;

    f32x4 acc[4][2];
#pragma unroll
    for (int mt = 0; mt < 4; ++mt)
#pragma unroll
        for (int nt = 0; nt < 2; ++nt) {
            f32x4 z = {0.f, 0.f, 0.f, 0.f};
            acc[mt][nt] = z;
        }

#define GEMM_STAGE(buf, kbl)                                                  \
    {                                                                         \
        const _Float16* ga = AB   + (size_t)(kbl) * 4096;                     \
        const _Float16* gh = WhiB + (size_t)(kbl) * 4096;                     \
        const _Float16* gl = WloB + (size_t)(kbl) * 4096;                     \
        int cb = w * 64;                                                      \
        async_copy16(&sA [buf][cb * 8],         ga + (size_t)(cb + lane) * 8);        \
        async_copy16(&sA [buf][(cb + 256) * 8], ga + (size_t)(cb + 256 + lane) * 8);  \
        async_copy16(&sBh[buf][cb * 8],         gh + (size_t)(cb + lane) * 8);        \
        async_copy16(&sBl[buf][cb * 8],         gl + (size_t)(cb + lane) * 8);        \
    }

    GEMM_STAGE(0, 0);

    for (int kb = 0; kb < 32; ++kb) {
        const int cur = kb & 1;
        if (kb + 1 < 32) {
            GEMM_STAGE(cur ^ 1, kb + 1);
            VMCNT(4);           // stage(cur) done; stage(next) in flight
        } else {
            VMCNT(0);
        }
        wg_barrier();

        half8_t af[4], bf[2], blv[2];
#pragma unroll
        for (int mt = 0; mt < 4; ++mt)
            af[mt] = *(const half8_t*)&sA[cur][(((wm * 4 + mt) * 64) + lane) * 8];
#pragma unroll
        for (int nt = 0; nt < 2; ++nt) {
            bf[nt]  = *(const half8_t*)&sBh[cur][(((wn * 2 + nt) * 64) + lane) * 8];
            blv[nt] = *(const half8_t*)&sBl[cur][(((wn * 2 + nt) * 64) + lane) * 8];
        }
#pragma unroll
        for (int mt = 0; mt < 4; ++mt)
#pragma unroll
            for (int nt = 0; nt < 2; ++nt) {
                acc[mt][nt] = __builtin_amdgcn_mfma_f32_16x16x32_f16(af[mt], bf[nt],  acc[mt][nt], 0, 0, 0);
                acc[mt][nt] = __builtin_amdgcn_mfma_f32_16x16x32_f16(af[mt], blv[nt], acc[mt][nt], 0, 0, 0);
            }
        LGKMCNT0();             // LDS reads of buf[cur] retired
        wg_barrier();           // safe for next iter's DMA to overwrite
    }

    if constexpr (MODE == 0) {
        // kind: 0=q (rope, scale), 1=k (rope), 2=v (direct interleave)
        const float* bias; int hh, kind;
        if (nj < 16)      { bias = bq; hh = nj;      kind = 0; }
        else if (nj < 20) { bias = bk; hh = nj - 16; kind = 1; }
        else              { bias = bv; hh = nj - 20; kind = 2; }
        const int b_ = mb >> 4;
        float bias2[2];
#pragma unroll
        for (int nt = 0; nt < 2; ++nt)
            bias2[nt] = bias[hh * 64 + wn * 32 + nt * 16 + l15];

        if (kind == 2) {
            // lane (quad,l15), mt-pair j: one vth unit per (j,nt):
            // u = 2*wm+j, dt = 2*wn+nt, keys {32u+4quad+r, +16+r} = acc rows.
            const int bhk = b_ * NKV + hh;
            const int kt2 = mb & 15;
            _Float16* base = vth + (size_t)(bhk * 16 + kt2) * 1024 * 8;
#pragma unroll
            for (int j = 0; j < 2; ++j)
#pragma unroll
                for (int nt = 0; nt < 2; ++nt) {
                    int u = wm * 2 + j, dt = wn * 2 + nt;
                    half8_t hv;
#pragma unroll
                    for (int r = 0; r < 4; ++r) {
                        hv[r]     = (_Float16)(acc[2 * j][nt][r]     + bias2[nt]);
                        hv[4 + r] = (_Float16)(acc[2 * j + 1][nt][r] + bias2[nt]);
                    }
                    int c = u * 256 + dt * 64 + quad * 16 + l15;
                    *(half8_t*)(base + (size_t)c * 8) = hv;
                }
        } else {
            // stage 128x64 fp32 tile (swizzled: col ^ ((row>>2)&7)<<2)
            float* tile = (float*)smem;
#pragma unroll
            for (int mt = 0; mt < 4; ++mt)
#pragma unroll
                for (int nt = 0; nt < 2; ++nt)
#pragma unroll
                    for (int r = 0; r < 4; ++r) {
                        int rr  = wm * 64 + mt * 16 + quad * 4 + r;
                        int col = wn * 32 + nt * 16 + l15;
                        int sc_ = col ^ (((rr >> 2) & 7) << 2);
                        tile[rr * 64 + sc_] = acc[mt][nt][r] + bias2[nt];
                    }
            __syncthreads();
            // rope: thread = (row rr, half ih); i = 16*ih + ii, ii=0..15
            // out[i]    = x[i]*c    - x[2i+1]*s
            // out[i+32] = x[i+32]*c + x[2i]*s
            const int rr = tid >> 1, ih = tid & 1;
            const int t_ = (mb & 15) * 128 + rr;
            const int swz = ((rr >> 2) & 7) << 2;
            const float* trow = tile + rr * 64;
            const float sc = (kind == 0) ? 0.125f : 1.0f;
            _Float16* dst = ((kind == 0) ? qh : kh) +
                ((size_t)(b_ * ((kind == 0) ? NH : NKV) + hh) * T_ + t_) * 64;
            half8_t lo0, lo1, hi0, hi1;
#pragma unroll
            for (int ii = 0; ii < 16; ++ii) {
                int i = ih * 16 + ii;
                float2 cs = tab[t_ * 32 + i];
                float x0 = trow[i ^ swz];
                float x1 = trow[(i + 32) ^ swz];
                float xe = trow[(2 * i) ^ swz];
                float xo = trow[(2 * i + 1) ^ swz];
                float olo = (x0 * cs.x - xo * cs.y) * sc;
                float ohi = (x1 * cs.x + xe * cs.y) * sc;
                if (ii < 8) { lo0[ii] = (_Float16)olo; hi0[ii] = (_Float16)ohi; }
                else        { lo1[ii - 8] = (_Float16)olo; hi1[ii - 8] = (_Float16)ohi; }
            }
            *(half8_t*)(dst + ih * 16)          = lo0;
            *(half8_t*)(dst + ih * 16 + 8)      = lo1;
            *(half8_t*)(dst + 32 + ih * 16)     = hi0;
            *(half8_t*)(dst + 32 + ih * 16 + 8) = hi1;
        }
    } else {
        const int m0 = mb * 128;
        int n0 = nblk * 64 + wn * 32;
#pragma unroll
        for (int mt = 0; mt < 4; ++mt)
#pragma unroll
            for (int r = 0; r < 4; ++r) {
                int m = m0 + wm * 64 + mt * 16 + quad * 4 + r;
#pragma unroll
                for (int nt = 0; nt < 2; ++nt) {
                    int n = n0 + nt * 16 + l15;
                    o0f[(size_t)m * 1024 + n] = acc[mt][nt][r] + bq[n];
                }
            }
    }
#undef GEMM_STAGE
}

// ---------------------------------------------------------------------------
// Kernel 6: flash attention, 128 q/block, 32 q/wave, KVBLK=128. Unchanged
// from round 9 (51us, 0 bank conflicts, MfmaUtil 41%).
// ---------------------------------------------------------------------------
__global__ __launch_bounds__(256, 2) void attn_kernel(
    const _Float16* __restrict__ qh, const _Float16* __restrict__ kh,
    const _Float16* __restrict__ vth, _Float16* __restrict__ ctx_h)
{
    __shared__ _Float16 Ks[2][8192];
    __shared__ _Float16 Vs[2][8192];

    const int qt = blockIdx.x;          // 0..15 (128-q tiles)
    const int bh = blockIdx.y;          // 0..31
    const int b  = bh >> 4, h = bh & 15, hk = h >> 2;
    const int tid  = threadIdx.x;
    const int w    = tid >> 6;
    const int lane = tid & 63;
    const int quad = lane >> 4, l15 = lane & 15;

    // Q B-frags for 2 strips of 16 q-rows (q pre-scaled by 0.125 at rope)
    half8_t aq0[2], aq1[2];
#pragma unroll
    for (int s = 0; s < 2; ++s) {
        const _Float16* Qb = qh +
            ((size_t)(b * NH + h) * T_ + qt * 128 + w * 32 + s * 16 + l15) * 64 + quad * 8;
        aq0[s] = *(const half8_t*)(Qb);
        aq1[s] = *(const half8_t*)(Qb + 32);
    }
    // Force Q loads resolved here -> no compiler vmcnt waits inside the loop.
    asm volatile("" :: "v"(aq0[0]), "v"(aq0[1]), "v"(aq1[0]), "v"(aq1[1]));

    const _Float16* Kb = kh  + (size_t)(b * NKV + hk) * (T_ * 64);
    const _Float16* Vb = vth + (size_t)(b * NKV + hk) * (64 * T_);

    // Stage one 128-key tile-pair: K 1024 chunks + V 1024 chunks, 8 DMA/thread.
#define ATTN_STAGE(buf, ktile)                                                \
    {                                                                         \
        _Float16* kd = &Ks[buf][0];                                           \
        _Float16* vd = &Vs[buf][0];                                           \
        _Pragma("unroll")                                                     \
        for (int p = 0; p < 4; ++p) {                                         \
            int cb = p * 256 + w * 64;                                        \
            int c  = cb + lane;                                               \
            int kl = c & 15, kq = (c >> 4) & 3, ktt = (c >> 6) & 7, kr = c >> 9; \
            const _Float16* kg = Kb + ((size_t)((ktile) * 128 + ktt * 16 + kl)) * 64 + (kr * 4 + kq) * 8; \
            const _Float16* vg = Vb + ((size_t)(ktile) * 1024 + c) * 8;       \
            async_copy16(kd + cb * 8, kg);                                    \
            async_copy16(vd + cb * 8, vg);                                    \
        }                                                                     \
    }

    float l_i[2] = {0.0f, 0.0f};
    f32x4 o_acc[2][4];
#pragma unroll
    for (int s = 0; s < 2; ++s)
#pragma unroll
        for (int dt = 0; dt < 4; ++dt) { f32x4 z = {0.f,0.f,0.f,0.f}; o_acc[s][dt] = z; }

    ATTN_STAGE(0, 0);

    for (int kt = 0; kt < T_ / 128; ++kt) {
        const int cur = kt & 1;
        if (kt + 1 < T_ / 128) {
            ATTN_STAGE(cur ^ 1, kt + 1);
            VMCNT(8);           // wait stage(cur) only; stage(next) in flight
        } else {
            VMCNT(0);
        }
        wg_barrier();           // buf[cur] ready across all waves

#pragma unroll
        for (int u = 0; u < 4; ++u) {
            // K frags for t=2u, 2u+1: wave-contiguous 1KiB b128 reads
            half8_t ak0[2], ak1[2];
#pragma unroll
            for (int tt = 0; tt < 2; ++tt) {
                const _Float16* kr_ = &Ks[cur][((2 * u + tt) * 64 + lane) * 8];
                ak0[tt] = *(const half8_t*)(kr_);
                ak1[tt] = *(const half8_t*)(kr_ + 4096);
            }
            // V frags: one b128 per (u,dt) holds both t halves (interleaved)
            half8_t av8[4];
#pragma unroll
            for (int dt = 0; dt < 4; ++dt)
                av8[dt] = *(const half8_t*)&Vs[cur][((u * 4 + dt) * 64 + lane) * 8];

#pragma unroll
            for (int s = 0; s < 2; ++s) {
#pragma unroll
                for (int tt = 0; tt < 2; ++tt) {
                    f32x4 z = {0.f,0.f,0.f,0.f};
                    z = __builtin_amdgcn_mfma_f32_16x16x32_f16(ak0[tt], aq0[s], z, 0, 0, 0);
                    f32x4 sv = __builtin_amdgcn_mfma_f32_16x16x32_f16(ak1[tt], aq1[s], z, 0, 0, 0);
                    float p0 = __expf(sv[0]);
                    float p1 = __expf(sv[1]);
                    float p2 = __expf(sv[2]);
                    float p3 = __expf(sv[3]);
                    l_i[s] += (p0 + p1) + (p2 + p3);
                    half4_t pb;
                    pb[0] = (_Float16)p0; pb[1] = (_Float16)p1;
                    pb[2] = (_Float16)p2; pb[3] = (_Float16)p3;
#pragma unroll
                    for (int dt = 0; dt < 4; ++dt) {
                        half4_t a = tt
                            ? __builtin_shufflevector(av8[dt], av8[dt], 4, 5, 6, 7)
                            : __builtin_shufflevector(av8[dt], av8[dt], 0, 1, 2, 3);
                        o_acc[s][dt] = __builtin_amdgcn_mfma_f32_16x16x16f16(
                            a, pb, o_acc[s][dt], 0, 0, 0);
                    }
                }
            }
        }
        LGKMCNT0();             // all LDS reads of buf[cur] retired
        wg_barrier();           // safe for next iter's DMA to overwrite
    }

    // epilogue: reduce l across quads (lane bits 4,5), normalize, store fp16
    // into ctx chunks: idx = (mb*32+kb)*512 + (ml>>4)*64 + k8*16 + (ml&15)
    const int mb = b * 16 + qt;
#pragma unroll
    for (int s = 0; s < 2; ++s) {
        float l = l_i[s];
        l += __shfl_xor(l, 16);
        l += __shfl_xor(l, 32);
        float inv = 1.0f / l;
        // ml = w*32 + s*16 + l15  ->  ml>>4 = 2w+s, ml&15 = l15
#pragma unroll
        for (int dt = 0; dt < 4; ++dt)
#pragma unroll
            for (int r = 0; r < 4; ++r) {
                int d   = 16 * dt + 4 * quad + r;
                int kb_ = 2 * h + (d >> 5);
                int k8  = (d >> 3) & 3;
                int j   = d & 7;
                size_t idx = (size_t)(mb * 32 + kb_) * 512 + (w * 2 + s) * 64 + k8 * 16 + l15;
                ctx_h[idx * 8 + j] = (_Float16)(o_acc[s][dt][r] * inv);
            }
    }
#undef ATTN_STAGE
}

// ---------------------------------------------------------------------------
extern "C" void kernel_launch(void* const* d_in, const int* in_sizes, int n_in,
                              void* d_out, int out_size, void* d_ws, size_t ws_size,
                              hipStream_t stream)
{
    const float* hs = (const float*)d_in[0];
    const float* Wq = (const float*)d_in[1];
    const float* bq = (const float*)d_in[2];
    const float* Wk = (const float*)d_in[3];
    const float* bk = (const float*)d_in[4];
    const float* Wv = (const float*)d_in[5];
    const float* bv = (const float*)d_in[6];
    const float* Wo = (const float*)d_in[7];
    const float* bo = (const float*)d_in[8];
    float* out = (float*)d_out;

    const size_t MB = 1024 * 1024;
    if (ws_size < 46 * MB) return;

    char* w = (char*)d_ws;
    _Float16* Whi  = (_Float16*)(w);              // 5 MB  [0,5)
    _Float16* Wlo  = (_Float16*)(w + 5 * MB);     // 5 MB  [5,10)
    _Float16* hs_h = (_Float16*)(w + 10 * MB);    // 8 MB  [10,18) A chunks
    _Float16* qh   = (_Float16*)(w + 18 * MB);    // 8 MB  [18,26)
    _Float16* kh   = (_Float16*)(w + 26 * MB);    // 2 MB  [26,28)
    _Float16* vth  = (_Float16*)(w + 28 * MB);    // 2 MB  [28,30)
    float2*   tab  = (float2*)(w + 30 * MB);      // 0.5MB [30,30.5)
    // ctx aliases hs_h: A chunks dead once gemm<0> completes; attn (which
    // writes ctx) runs strictly after.
    _Float16* ctx_h = hs_h;

    prep_all_kernel<<<3584, 256, 0, stream>>>(
        tab, Wq, Wk, Wv, Wo, Whi, Wlo, hs, hs_h);
    gemm2p_kernel<0><<<dim3(32, 24), 256, 0, stream>>>(
        hs_h, Whi, Wlo, 0, bq, bk, bv, tab, nullptr, qh, kh, vth);
    attn_kernel<<<dim3(T_ / 128, B_ * NH), 256, 0, stream>>>(qh, kh, vth, ctx_h);
    gemm2p_kernel<1><<<dim3(32, 16), 256, 0, stream>>>(
        ctx_h, Whi, Wlo, 24, bo, nullptr, nullptr, tab, out, nullptr, nullptr, nullptr);
}

// Round 8
// 189.066 us; speedup vs baseline: 1.3200x; 1.0269x over previous
//
#include <hip/hip_runtime.h>
#include <math.h>

// GQA block. Round 12: store-coalescing + pipeline-depth pass.
// (a) prep_all iterates OUTPUT-linear: all 28MB of chunk stores are
//     wave-contiguous (was: scattered 16B granules); reads become row-gathers
//     that still cover full cache lines across the wave. Same values.
// (b) GEMM: 3-buffer depth-2 prefetch (vmcnt(8) steady state, 48KB LDS,
//     still 3 blocks/CU) -- doubles DMA latency window per tile.
// (c) attn ctx epilogue: 4 r-values per (s,dt) land at consecutive j ->
//     packed half4 stores (8 per thread, was 32 scalar 2B). Main loop
//     untouched (51us, 0 conflicts).
// Shapes: B=2, T=2048, DIM=1024, H=16, HKV=4, HD=64.

#define B_   2
#define T_   2048
#define DIM_ 1024
#define NH   16
#define NKV  4
#define HD_  64
#define BT_  (B_ * T_)

typedef _Float16 half8_t __attribute__((ext_vector_type(8)));
typedef _Float16 half4_t __attribute__((ext_vector_type(4)));
typedef float    f32x4   __attribute__((ext_vector_type(4)));

__device__ __forceinline__ void async_copy16(_Float16* lds, const _Float16* g) {
    __builtin_amdgcn_global_load_lds(
        (const __attribute__((address_space(1))) void*)g,
        (__attribute__((address_space(3))) void*)lds, 16, 0, 0);
}

#define VMCNT(n) asm volatile("s_waitcnt vmcnt(" #n ")" ::: "memory")
#define LGKMCNT0() asm volatile("s_waitcnt lgkmcnt(0)" ::: "memory")

__device__ __forceinline__ void wg_barrier() {
    asm volatile("" ::: "memory");
    __builtin_amdgcn_s_barrier();
    asm volatile("" ::: "memory");
}

// ---------------------------------------------------------------------------
// Kernel 1: fused prep, OUTPUT-LINEAR. Block ranges:
//   [0,256):     RoPE sincos table tab[t*32+i]
//   [256,1536):  weight prep -> fp16 hi/lo chunk planes (coalesced stores)
//   [1536,3584): A prep      -> fp16 chunks (coalesced stores)
// Chunk idx bits: l15[0:3] k8[4:5] u7[6:8] kb[9:13] nb[14:]; holds
// X[nb*128 + u7*16 + l15][kb*32 + k8*8 .. +8].
// ---------------------------------------------------------------------------
__global__ __launch_bounds__(256) void prep_all_kernel(
    float2* __restrict__ tab,
    const float* __restrict__ Wq, const float* __restrict__ Wk,
    const float* __restrict__ Wv, const float* __restrict__ Wo,
    _Float16* __restrict__ Whi, _Float16* __restrict__ Wlo,
    const float* __restrict__ hs, _Float16* __restrict__ Ah)
{
    const int bid = blockIdx.x;
    const int tid = threadIdx.x;
    if (bid < 256) {
        int gid = bid * 256 + tid;                // 0..65535
        int t = gid >> 5, i = gid & 31;
        double invf = pow(10000.0, -(double)i / 32.0);
        double ang  = (double)t * invf;
        tab[gid] = make_float2((float)cos(ang), (float)sin(ang));
    } else if (bid < 1536) {
        int idx = (bid - 256) * 256 + tid;        // 0..327679 output chunk
        int l15 = idx & 15, k8 = (idx >> 4) & 3, u7 = (idx >> 6) & 7;
        int kb = (idx >> 9) & 31, nb = idx >> 14;
        int n = nb * 128 + u7 * 16 + l15, k = kb * 32 + k8 * 8;
        const float* src;
        if (n < 1024)      src = Wq + (size_t)n * 1024;
        else if (n < 1280) src = Wk + (size_t)(n - 1024) * 1024;
        else if (n < 1536) src = Wv + (size_t)(n - 1280) * 1024;
        else               src = Wo + (size_t)(n - 1536) * 1024;
        float4 f0 = *(const float4*)(src + k);
        float4 f1 = *(const float4*)(src + k + 4);
        float xs[8] = {f0.x, f0.y, f0.z, f0.w, f1.x, f1.y, f1.z, f1.w};
        half8_t hi, lo;
#pragma unroll
        for (int j = 0; j < 8; ++j) {
            _Float16 h = (_Float16)xs[j];
            hi[j] = h;
            lo[j] = (_Float16)(xs[j] - (float)h);
        }
        *(half8_t*)&Whi[(size_t)idx * 8] = hi;
        *(half8_t*)&Wlo[(size_t)idx * 8] = lo;
    } else {
        int idx = (bid - 1536) * 256 + tid;       // 0..524287 output chunk
        int l15 = idx & 15, k8 = (idx >> 4) & 3, u7 = (idx >> 6) & 7;
        int kb = (idx >> 9) & 31, mb = idx >> 14;
        const float* src = hs + (size_t)(mb * 128 + u7 * 16 + l15) * 1024
                              + kb * 32 + k8 * 8;
        float4 f0 = *(const float4*)src;
        float4 f1 = *(const float4*)(src + 4);
        half8_t hv;
        hv[0] = (_Float16)f0.x; hv[1] = (_Float16)f0.y;
        hv[2] = (_Float16)f0.z; hv[3] = (_Float16)f0.w;
        hv[4] = (_Float16)f1.x; hv[5] = (_Float16)f1.y;
        hv[6] = (_Float16)f1.z; hv[7] = (_Float16)f1.w;
        *(half8_t*)&Ah[(size_t)idx * 8] = hv;
    }
}

// ---------------------------------------------------------------------------
// Kernel 3: 2-pass MFMA GEMM, all-DMA staging. C = A @ (Whi+Wlo)^T + bias.
// 128x64 tile, BK=32, 3-buffer depth-2 prefetch (vmcnt(8)), 4 waves as 2x2.
// MODE 0: fused epilogue -- q/k: LDS-staged rope -> fp16 qh/kh;
//         v: direct interleaved vth stores.  MODE 1: row-major fp32 + bias.
// ---------------------------------------------------------------------------
template <int MODE>
__global__ __launch_bounds__(256, 3) void gemm2p_kernel(
    const _Float16* __restrict__ Ah,
    const _Float16* __restrict__ Whi, const _Float16* __restrict__ Wlo,
    int nj0,
    const float* __restrict__ bq, const float* __restrict__ bk,
    const float* __restrict__ bv,
    const float2* __restrict__ tab,
    float* __restrict__ o0f,
    _Float16* __restrict__ qh, _Float16* __restrict__ kh,
    _Float16* __restrict__ vth)
{
    // 48KB: 3 staging bufs (sA 8K | sBh 4K | sBl 4K each); MODE0 epilogue
    // reuses the first 32KB as a 128x64 fp32 tile.
    __shared__ __align__(16) char smem[49152];
    _Float16 (*sA )[4096] = (_Float16(*)[4096])(smem);
    _Float16 (*sBh)[2048] = (_Float16(*)[2048])(smem + 24576);
    _Float16 (*sBl)[2048] = (_Float16(*)[2048])(smem + 36864);

    const int tid  = threadIdx.x;
    const int w    = tid >> 6, lane = tid & 63;
    const int quad = lane >> 4, l15 = lane & 15;
    const int wm = w >> 1, wn = w & 1;
    const int mb   = blockIdx.x;          // x = row tile (W-panel L2 reuse)
    const int nblk = blockIdx.y;
    const int nj   = nj0 + nblk;

    const _Float16* AB   = Ah  + (size_t)mb * 32 * 4096;
    const size_t woff = (size_t)(nj >> 1) * 32 * 4096 + (size_t)(nj & 1) * 2048;
    const _Float16* WhiB = Whi + woff;
    const _Float16* WloB = Wlo + woff;

    f32x4 acc[4][2];
#pragma unroll
    for (int mt = 0; mt < 4; ++mt)
#pragma unroll
        for (int nt = 0; nt < 2; ++nt) {
            f32x4 z = {0.f, 0.f, 0.f, 0.f};
            acc[mt][nt] = z;
        }

#define GEMM_STAGE(buf, kbl)                                                  \
    {                                                                         \
        const _Float16* ga = AB   + (size_t)(kbl) * 4096;                     \
        const _Float16* gh = WhiB + (size_t)(kbl) * 4096;                     \
        const _Float16* gl = WloB + (size_t)(kbl) * 4096;                     \
        int cb = w * 64;                                                      \
        async_copy16(&sA [buf][cb * 8],         ga + (size_t)(cb + lane) * 8);        \
        async_copy16(&sA [buf][(cb + 256) * 8], ga + (size_t)(cb + 256 + lane) * 8);  \
        async_copy16(&sBh[buf][cb * 8],         gh + (size_t)(cb + lane) * 8);        \
        async_copy16(&sBl[buf][cb * 8],         gl + (size_t)(cb + lane) * 8);        \
    }

    GEMM_STAGE(0, 0);
    GEMM_STAGE(1, 1);

    for (int kb = 0; kb < 32; ++kb) {
        const int cur = kb % 3;
        if (kb + 2 < 32) {
            GEMM_STAGE((kb + 2) % 3, kb + 2);
            VMCNT(8);           // stage(kb) done; kb+1, kb+2 in flight
        } else if (kb + 1 < 32) {
            VMCNT(4);           // stage(kb) done; kb+1 in flight
        } else {
            VMCNT(0);
        }
        wg_barrier();

        half8_t af[4], bf[2], blv[2];
#pragma unroll
        for (int mt = 0; mt < 4; ++mt)
            af[mt] = *(const half8_t*)&sA[cur][(((wm * 4 + mt) * 64) + lane) * 8];
#pragma unroll
        for (int nt = 0; nt < 2; ++nt) {
            bf[nt]  = *(const half8_t*)&sBh[cur][(((wn * 2 + nt) * 64) + lane) * 8];
            blv[nt] = *(const half8_t*)&sBl[cur][(((wn * 2 + nt) * 64) + lane) * 8];
        }
#pragma unroll
        for (int mt = 0; mt < 4; ++mt)
#pragma unroll
            for (int nt = 0; nt < 2; ++nt) {
                acc[mt][nt] = __builtin_amdgcn_mfma_f32_16x16x32_f16(af[mt], bf[nt],  acc[mt][nt], 0, 0, 0);
                acc[mt][nt] = __builtin_amdgcn_mfma_f32_16x16x32_f16(af[mt], blv[nt], acc[mt][nt], 0, 0, 0);
            }
        LGKMCNT0();             // LDS reads of buf[cur] retired
        wg_barrier();           // safe for stage(kb+3) to overwrite buf[cur]
    }

    if constexpr (MODE == 0) {
        // kind: 0=q (rope, scale), 1=k (rope), 2=v (direct interleave)
        const float* bias; int hh, kind;
        if (nj < 16)      { bias = bq; hh = nj;      kind = 0; }
        else if (nj < 20) { bias = bk; hh = nj - 16; kind = 1; }
        else              { bias = bv; hh = nj - 20; kind = 2; }
        const int b_ = mb >> 4;
        float bias2[2];
#pragma unroll
        for (int nt = 0; nt < 2; ++nt)
            bias2[nt] = bias[hh * 64 + wn * 32 + nt * 16 + l15];

        if (kind == 2) {
            // lane (quad,l15), mt-pair j: one vth unit per (j,nt):
            // u = 2*wm+j, dt = 2*wn+nt, keys {32u+4quad+r, +16+r} = acc rows.
            const int bhk = b_ * NKV + hh;
            const int kt2 = mb & 15;
            _Float16* base = vth + (size_t)(bhk * 16 + kt2) * 1024 * 8;
#pragma unroll
            for (int j = 0; j < 2; ++j)
#pragma unroll
                for (int nt = 0; nt < 2; ++nt) {
                    int u = wm * 2 + j, dt = wn * 2 + nt;
                    half8_t hv;
#pragma unroll
                    for (int r = 0; r < 4; ++r) {
                        hv[r]     = (_Float16)(acc[2 * j][nt][r]     + bias2[nt]);
                        hv[4 + r] = (_Float16)(acc[2 * j + 1][nt][r] + bias2[nt]);
                    }
                    int c = u * 256 + dt * 64 + quad * 16 + l15;
                    *(half8_t*)(base + (size_t)c * 8) = hv;
                }
        } else {
            // stage 128x64 fp32 tile (swizzled: col ^ ((row>>2)&7)<<2)
            float* tile = (float*)smem;
#pragma unroll
            for (int mt = 0; mt < 4; ++mt)
#pragma unroll
                for (int nt = 0; nt < 2; ++nt)
#pragma unroll
                    for (int r = 0; r < 4; ++r) {
                        int rr  = wm * 64 + mt * 16 + quad * 4 + r;
                        int col = wn * 32 + nt * 16 + l15;
                        int sc_ = col ^ (((rr >> 2) & 7) << 2);
                        tile[rr * 64 + sc_] = acc[mt][nt][r] + bias2[nt];
                    }
            __syncthreads();
            // rope: thread = (row rr, half ih); i = 16*ih + ii, ii=0..15
            const int rr = tid >> 1, ih = tid & 1;
            const int t_ = (mb & 15) * 128 + rr;
            const int swz = ((rr >> 2) & 7) << 2;
            const float* trow = tile + rr * 64;
            const float sc = (kind == 0) ? 0.125f : 1.0f;
            _Float16* dst = ((kind == 0) ? qh : kh) +
                ((size_t)(b_ * ((kind == 0) ? NH : NKV) + hh) * T_ + t_) * 64;
            half8_t lo0, lo1, hi0, hi1;
#pragma unroll
            for (int ii = 0; ii < 16; ++ii) {
                int i = ih * 16 + ii;
                float2 cs = tab[t_ * 32 + i];
                float x0 = trow[i ^ swz];
                float x1 = trow[(i + 32) ^ swz];
                float xe = trow[(2 * i) ^ swz];
                float xo = trow[(2 * i + 1) ^ swz];
                float olo = (x0 * cs.x - xo * cs.y) * sc;
                float ohi = (x1 * cs.x + xe * cs.y) * sc;
                if (ii < 8) { lo0[ii] = (_Float16)olo; hi0[ii] = (_Float16)ohi; }
                else        { lo1[ii - 8] = (_Float16)olo; hi1[ii - 8] = (_Float16)ohi; }
            }
            *(half8_t*)(dst + ih * 16)          = lo0;
            *(half8_t*)(dst + ih * 16 + 8)      = lo1;
            *(half8_t*)(dst + 32 + ih * 16)     = hi0;
            *(half8_t*)(dst + 32 + ih * 16 + 8) = hi1;
        }
    } else {
        const int m0 = mb * 128;
        int n0 = nblk * 64 + wn * 32;
#pragma unroll
        for (int mt = 0; mt < 4; ++mt)
#pragma unroll
            for (int r = 0; r < 4; ++r) {
                int m = m0 + wm * 64 + mt * 16 + quad * 4 + r;
#pragma unroll
                for (int nt = 0; nt < 2; ++nt) {
                    int n = n0 + nt * 16 + l15;
                    o0f[(size_t)m * 1024 + n] = acc[mt][nt][r] + bq[n];
                }
            }
    }
#undef GEMM_STAGE
}

// ---------------------------------------------------------------------------
// Kernel 6: flash attention, 128 q/block, 32 q/wave, KVBLK=128. Main loop
// unchanged (51us, 0 bank conflicts). Epilogue: packed half4 ctx stores.
// ---------------------------------------------------------------------------
__global__ __launch_bounds__(256, 2) void attn_kernel(
    const _Float16* __restrict__ qh, const _Float16* __restrict__ kh,
    const _Float16* __restrict__ vth, _Float16* __restrict__ ctx_h)
{
    __shared__ _Float16 Ks[2][8192];
    __shared__ _Float16 Vs[2][8192];

    const int qt = blockIdx.x;          // 0..15 (128-q tiles)
    const int bh = blockIdx.y;          // 0..31
    const int b  = bh >> 4, h = bh & 15, hk = h >> 2;
    const int tid  = threadIdx.x;
    const int w    = tid >> 6;
    const int lane = tid & 63;
    const int quad = lane >> 4, l15 = lane & 15;

    // Q B-frags for 2 strips of 16 q-rows (q pre-scaled by 0.125 at rope)
    half8_t aq0[2], aq1[2];
#pragma unroll
    for (int s = 0; s < 2; ++s) {
        const _Float16* Qb = qh +
            ((size_t)(b * NH + h) * T_ + qt * 128 + w * 32 + s * 16 + l15) * 64 + quad * 8;
        aq0[s] = *(const half8_t*)(Qb);
        aq1[s] = *(const half8_t*)(Qb + 32);
    }
    // Force Q loads resolved here -> no compiler vmcnt waits inside the loop.
    asm volatile("" :: "v"(aq0[0]), "v"(aq0[1]), "v"(aq1[0]), "v"(aq1[1]));

    const _Float16* Kb = kh  + (size_t)(b * NKV + hk) * (T_ * 64);
    const _Float16* Vb = vth + (size_t)(b * NKV + hk) * (64 * T_);

    // Stage one 128-key tile-pair: K 1024 chunks + V 1024 chunks, 8 DMA/thread.
#define ATTN_STAGE(buf, ktile)                                                \
    {                                                                         \
        _Float16* kd = &Ks[buf][0];                                           \
        _Float16* vd = &Vs[buf][0];                                           \
        _Pragma("unroll")                                                     \
        for (int p = 0; p < 4; ++p) {                                         \
            int cb = p * 256 + w * 64;                                        \
            int c  = cb + lane;                                               \
            int kl = c & 15, kq = (c >> 4) & 3, ktt = (c >> 6) & 7, kr = c >> 9; \
            const _Float16* kg = Kb + ((size_t)((ktile) * 128 + ktt * 16 + kl)) * 64 + (kr * 4 + kq) * 8; \
            const _Float16* vg = Vb + ((size_t)(ktile) * 1024 + c) * 8;       \
            async_copy16(kd + cb * 8, kg);                                    \
            async_copy16(vd + cb * 8, vg);                                    \
        }                                                                     \
    }

    float l_i[2] = {0.0f, 0.0f};
    f32x4 o_acc[2][4];
#pragma unroll
    for (int s = 0; s < 2; ++s)
#pragma unroll
        for (int dt = 0; dt < 4; ++dt) { f32x4 z = {0.f,0.f,0.f,0.f}; o_acc[s][dt] = z; }

    ATTN_STAGE(0, 0);

    for (int kt = 0; kt < T_ / 128; ++kt) {
        const int cur = kt & 1;
        if (kt + 1 < T_ / 128) {
            ATTN_STAGE(cur ^ 1, kt + 1);
            VMCNT(8);           // wait stage(cur) only; stage(next) in flight
        } else {
            VMCNT(0);
        }
        wg_barrier();           // buf[cur] ready across all waves

#pragma unroll
        for (int u = 0; u < 4; ++u) {
            // K frags for t=2u, 2u+1: wave-contiguous 1KiB b128 reads
            half8_t ak0[2], ak1[2];
#pragma unroll
            for (int tt = 0; tt < 2; ++tt) {
                const _Float16* kr_ = &Ks[cur][((2 * u + tt) * 64 + lane) * 8];
                ak0[tt] = *(const half8_t*)(kr_);
                ak1[tt] = *(const half8_t*)(kr_ + 4096);
            }
            // V frags: one b128 per (u,dt) holds both t halves (interleaved)
            half8_t av8[4];
#pragma unroll
            for (int dt = 0; dt < 4; ++dt)
                av8[dt] = *(const half8_t*)&Vs[cur][((u * 4 + dt) * 64 + lane) * 8];

#pragma unroll
            for (int s = 0; s < 2; ++s) {
#pragma unroll
                for (int tt = 0; tt < 2; ++tt) {
                    f32x4 z = {0.f,0.f,0.f,0.f};
                    z = __builtin_amdgcn_mfma_f32_16x16x32_f16(ak0[tt], aq0[s], z, 0, 0, 0);
                    f32x4 sv = __builtin_amdgcn_mfma_f32_16x16x32_f16(ak1[tt], aq1[s], z, 0, 0, 0);
                    float p0 = __expf(sv[0]);
                    float p1 = __expf(sv[1]);
                    float p2 = __expf(sv[2]);
                    float p3 = __expf(sv[3]);
                    l_i[s] += (p0 + p1) + (p2 + p3);
                    half4_t pb;
                    pb[0] = (_Float16)p0; pb[1] = (_Float16)p1;
                    pb[2] = (_Float16)p2; pb[3] = (_Float16)p3;
#pragma unroll
                    for (int dt = 0; dt < 4; ++dt) {
                        half4_t a = tt
                            ? __builtin_shufflevector(av8[dt], av8[dt], 4, 5, 6, 7)
                            : __builtin_shufflevector(av8[dt], av8[dt], 0, 1, 2, 3);
                        o_acc[s][dt] = __builtin_amdgcn_mfma_f32_16x16x16f16(
                            a, pb, o_acc[s][dt], 0, 0, 0);
                    }
                }
            }
        }
        LGKMCNT0();             // all LDS reads of buf[cur] retired
        wg_barrier();           // safe for next iter's DMA to overwrite
    }

    // epilogue: reduce l across quads, normalize, packed half4 ctx stores.
    // For fixed (s,dt): d = 16dt+4quad+r, r=0..3 -> j = 4*(quad&1)+r
    // (consecutive), kb_ = 2h + (dt>>1), k8 = (2dt + (quad>>1)) & 3.
    const int mb = b * 16 + qt;
#pragma unroll
    for (int s = 0; s < 2; ++s) {
        float l = l_i[s];
        l += __shfl_xor(l, 16);
        l += __shfl_xor(l, 32);
        float inv = 1.0f / l;
#pragma unroll
        for (int dt = 0; dt < 4; ++dt) {
            int kb_ = 2 * h + (dt >> 1);
            int k8  = (2 * dt + (quad >> 1)) & 3;
            size_t idx = (size_t)(mb * 32 + kb_) * 512 + (w * 2 + s) * 64 + k8 * 16 + l15;
            half4_t hv;
#pragma unroll
            for (int r = 0; r < 4; ++r)
                hv[r] = (_Float16)(o_acc[s][dt][r] * inv);
            *(half4_t*)&ctx_h[idx * 8 + 4 * (quad & 1)] = hv;
        }
    }
#undef ATTN_STAGE
}

// ---------------------------------------------------------------------------
extern "C" void kernel_launch(void* const* d_in, const int* in_sizes, int n_in,
                              void* d_out, int out_size, void* d_ws, size_t ws_size,
                              hipStream_t stream)
{
    const float* hs = (const float*)d_in[0];
    const float* Wq = (const float*)d_in[1];
    const float* bq = (const float*)d_in[2];
    const float* Wk = (const float*)d_in[3];
    const float* bk = (const float*)d_in[4];
    const float* Wv = (const float*)d_in[5];
    const float* bv = (const float*)d_in[6];
    const float* Wo = (const float*)d_in[7];
    const float* bo = (const float*)d_in[8];
    float* out = (float*)d_out;

    const size_t MB = 1024 * 1024;
    if (ws_size < 46 * MB) return;

    char* w = (char*)d_ws;
    _Float16* Whi  = (_Float16*)(w);              // 5 MB  [0,5)
    _Float16* Wlo  = (_Float16*)(w + 5 * MB);     // 5 MB  [5,10)
    _Float16* hs_h = (_Float16*)(w + 10 * MB);    // 8 MB  [10,18) A chunks
    _Float16* qh   = (_Float16*)(w + 18 * MB);    // 8 MB  [18,26)
    _Float16* kh   = (_Float16*)(w + 26 * MB);    // 2 MB  [26,28)
    _Float16* vth  = (_Float16*)(w + 28 * MB);    // 2 MB  [28,30)
    float2*   tab  = (float2*)(w + 30 * MB);      // 0.5MB [30,30.5)
    // ctx aliases hs_h: A chunks dead once gemm<0> completes; attn (which
    // writes ctx) runs strictly after.
    _Float16* ctx_h = hs_h;

    prep_all_kernel<<<3584, 256, 0, stream>>>(
        tab, Wq, Wk, Wv, Wo, Whi, Wlo, hs, hs_h);
    gemm2p_kernel<0><<<dim3(32, 24), 256, 0, stream>>>(
        hs_h, Whi, Wlo, 0, bq, bk, bv, tab, nullptr, qh, kh, vth);
    attn_kernel<<<dim3(T_ / 128, B_ * NH), 256, 0, stream>>>(qh, kh, vth, ctx_h);
    gemm2p_kernel<1><<<dim3(32, 16), 256, 0, stream>>>(
        ctx_h, Whi, Wlo, 24, bo, nullptr, nullptr, tab, out, nullptr, nullptr, nullptr);
}